// Round 1
// baseline (859.444 us; speedup 1.0000x reference)
//
#include <hip/hip_runtime.h>

typedef unsigned short u16;
typedef __attribute__((ext_vector_type(8))) short bf16x8;
typedef __attribute__((ext_vector_type(4))) float f32x4;

#define B_      2
#define L_      1024
#define DM      1024
#define DI      2048
#define NH      32
#define HD      64
#define DSTATE  64
#define CONVD   2176
#define DPROJ   4256

__device__ __forceinline__ u16 f2bf(float f) {
  union { float f; unsigned u; } v; v.f = f;
  unsigned r = v.u + 0x7fffu + ((v.u >> 16) & 1u);   // RNE
  return (u16)(r >> 16);
}

__device__ __forceinline__ float block_reduce_sum256(float v) {
  #pragma unroll
  for (int off = 32; off > 0; off >>= 1) v += __shfl_down(v, off, 64);
  __shared__ float red[4];
  int lane = threadIdx.x & 63, w = threadIdx.x >> 6;
  if (lane == 0) red[w] = v;
  __syncthreads();
  return red[0] + red[1] + red[2] + red[3];
}

// ---------------- f32 -> bf16 convert ----------------
__global__ __launch_bounds__(256) void f32_to_bf16(const float* __restrict__ in,
                                                   u16* __restrict__ out, int n4) {
  int i = blockIdx.x * 256 + threadIdx.x;
  if (i < n4) {
    float4 v = ((const float4*)in)[i];
    ((ushort4*)out)[i] = make_ushort4(f2bf(v.x), f2bf(v.y), f2bf(v.z), f2bf(v.w));
  }
}

// ---------------- rmsnorm (optionally fused residual add) ----------------
// cols fixed = 1024. in2/sum_out nullable.
__global__ __launch_bounds__(256) void add_rms_kernel(
    const float* __restrict__ in1, const float* __restrict__ in2,
    float* __restrict__ sum_out, const float* __restrict__ wt,
    u16* __restrict__ out, float eps) {
  const int row = blockIdx.x;
  const int c = threadIdx.x << 2;
  float4 v = *(const float4*)(in1 + (long)row * DM + c);
  if (in2) {
    float4 u = *(const float4*)(in2 + (long)row * DM + c);
    v.x += u.x; v.y += u.y; v.z += u.z; v.w += u.w;
  }
  if (sum_out) *(float4*)(sum_out + (long)row * DM + c) = v;
  float ss = v.x * v.x + v.y * v.y + v.z * v.z + v.w * v.w;
  float tot = block_reduce_sum256(ss);
  float sc = rsqrtf(tot * (1.0f / DM) + eps);
  float4 wv = *(const float4*)(wt + c);
  *(ushort4*)(out + (long)row * DM + c) =
      make_ushort4(f2bf(v.x * sc * wv.x), f2bf(v.y * sc * wv.y),
                   f2bf(v.z * sc * wv.z), f2bf(v.w * sc * wv.w));
}

// ---------------- bf16 NT GEMM: C[m,n] = sum_k A[m,k]*Bw[n,k] ----------------
// A: M x K row-major bf16, Bw: N x K row-major bf16, C: M x N f32.
// 128x128 tile, BK=64, 256 threads (4 waves, 2x2 of 64x64).
__global__ __launch_bounds__(256) void gemm_bf16_nt(
    const u16* __restrict__ A, const u16* __restrict__ Bw,
    float* __restrict__ C, int M, int N, int K) {
  __shared__ u16 As[128][72];   // +8 pad: 2-way max bank conflict on b128 reads
  __shared__ u16 Bs[128][72];
  const int tid = threadIdx.x;
  const int lane = tid & 63;
  const int wave = tid >> 6;
  const int wm = (wave & 1) << 6;
  const int wn = (wave >> 1) << 6;
  const int bm = blockIdx.y << 7;
  const int bn = blockIdx.x << 7;
  const int lrow = tid >> 3;          // 0..31
  const int lcol = (tid & 7) << 3;    // 0,8,..,56

  f32x4 acc[4][4];
  #pragma unroll
  for (int i = 0; i < 4; ++i)
    #pragma unroll
    for (int j = 0; j < 4; ++j)
      acc[i][j] = (f32x4){0.f, 0.f, 0.f, 0.f};

  const u16* Aptr = A + (long)(bm + lrow) * K + lcol;
  const u16* Bptr = Bw + (long)(bn + lrow) * K + lcol;

  uint4 ar[4], br[4];
  const uint4 z4 = make_uint4(0, 0, 0, 0);
  #pragma unroll
  for (int p = 0; p < 4; ++p) {
    ar[p] = *(const uint4*)(Aptr + (long)p * 32 * K);
    br[p] = (bn + lrow + p * 32 < N) ? *(const uint4*)(Bptr + (long)p * 32 * K) : z4;
  }

  for (int kt = 0; kt < K; kt += 64) {
    __syncthreads();
    #pragma unroll
    for (int p = 0; p < 4; ++p) {
      *(uint4*)&As[lrow + p * 32][lcol] = ar[p];
      *(uint4*)&Bs[lrow + p * 32][lcol] = br[p];
    }
    __syncthreads();
    if (kt + 64 < K) {
      #pragma unroll
      for (int p = 0; p < 4; ++p) {
        ar[p] = *(const uint4*)(Aptr + (kt + 64) + (long)p * 32 * K);
        br[p] = (bn + lrow + p * 32 < N) ? *(const uint4*)(Bptr + (kt + 64) + (long)p * 32 * K) : z4;
      }
    }
    #pragma unroll
    for (int ks = 0; ks < 2; ++ks) {
      const int krow = (ks << 5) + ((lane >> 4) << 3);
      bf16x8 af[4], bf[4];
      #pragma unroll
      for (int i = 0; i < 4; ++i)
        af[i] = *(const bf16x8*)&As[wm + (i << 4) + (lane & 15)][krow];
      #pragma unroll
      for (int j = 0; j < 4; ++j)
        bf[j] = *(const bf16x8*)&Bs[wn + (j << 4) + (lane & 15)][krow];
      #pragma unroll
      for (int i = 0; i < 4; ++i)
        #pragma unroll
        for (int j = 0; j < 4; ++j)
          acc[i][j] = __builtin_amdgcn_mfma_f32_16x16x32_bf16(af[i], bf[j], acc[i][j], 0, 0, 0);
    }
  }

  const int col = lane & 15;
  const int rquad = (lane >> 4) << 2;
  #pragma unroll
  for (int i = 0; i < 4; ++i) {
    const int gm = bm + wm + (i << 4) + rquad;
    #pragma unroll
    for (int j = 0; j < 4; ++j) {
      const int gn = bn + wn + (j << 4) + col;
      if (gn < N) {
        #pragma unroll
        for (int r = 0; r < 4; ++r)
          C[(long)(gm + r) * N + gn] = acc[i][j][r];
      }
    }
  }
}

// ---------------- dt softplus + dA ----------------
__global__ __launch_bounds__(256) void dtA_kernel(
    const float* __restrict__ zx, const float* __restrict__ dt_bias,
    const float* __restrict__ A_log, float* __restrict__ dts,
    float* __restrict__ dAa) {
  int idx = blockIdx.x * 256 + threadIdx.x;   // B_*L_*NH = 65536
  int h = idx & (NH - 1);
  int row = idx >> 5;
  float x = zx[(long)row * DPROJ + (DI + CONVD) + h] + dt_bias[h];
  float sp = (x > 20.f) ? x : log1pf(expf(x));
  dts[idx] = sp;
  dAa[idx] = expf(-expf(A_log[h]) * sp);
}

// ---------------- depthwise causal conv (k=4) + silu ----------------
__global__ __launch_bounds__(256) void conv_silu_kernel(
    const float* __restrict__ zx, const float* __restrict__ cw,
    const float* __restrict__ cb, float* __restrict__ xc) {
  int idx = blockIdx.x * 256 + threadIdx.x;
  if (idx >= 2048 * 544) return;
  const int c4 = (idx % 544) << 2;
  const int row = idx / 544;          // b*L + t
  const int t = row & (L_ - 1);
  float4 acc = *(const float4*)(cb + c4);
  float4 w0 = *(const float4*)(cw + (c4 + 0) * 4);
  float4 w1v = *(const float4*)(cw + (c4 + 1) * 4);
  float4 w2v = *(const float4*)(cw + (c4 + 2) * 4);
  float4 w3v = *(const float4*)(cw + (c4 + 3) * 4);
  const float wts[4][4] = {{w0.x, w0.y, w0.z, w0.w},
                           {w1v.x, w1v.y, w1v.z, w1v.w},
                           {w2v.x, w2v.y, w2v.z, w2v.w},
                           {w3v.x, w3v.y, w3v.z, w3v.w}};
  #pragma unroll
  for (int i = 0; i < 4; ++i) {
    int tau = t - 3 + i;
    if (tau >= 0) {
      float4 xv = *(const float4*)(zx + (long)(row - t + tau) * DPROJ + DI + c4);
      acc.x = fmaf(xv.x, wts[0][i], acc.x);
      acc.y = fmaf(xv.y, wts[1][i], acc.y);
      acc.z = fmaf(xv.z, wts[2][i], acc.z);
      acc.w = fmaf(xv.w, wts[3][i], acc.w);
    }
  }
  acc.x = acc.x / (1.f + expf(-acc.x));
  acc.y = acc.y / (1.f + expf(-acc.y));
  acc.z = acc.z / (1.f + expf(-acc.z));
  acc.w = acc.w / (1.f + expf(-acc.w));
  *(float4*)(xc + (long)row * CONVD + c4) = acc;
}

// ---------------- SSM scan ----------------
// grid: 256 = (b,h,pg); block: 64 (1 wave). lane -> (p_local = lane>>2, q = lane&3),
// each lane keeps h[p, 16q..16q+16) in registers. y = y + D*x fused.
__global__ __launch_bounds__(64) void scan_kernel(
    const float* __restrict__ xc, const float* __restrict__ dts,
    const float* __restrict__ dAa, const float* __restrict__ Dp,
    float* __restrict__ y) {
  const int blk = blockIdx.x;
  const int pg = blk & 3;
  const int h = (blk >> 2) & 31;
  const int b = blk >> 7;
  const int lane = threadIdx.x;
  const int pl = lane >> 2;   // 0..15
  const int q = lane & 3;     // n-range [16q, 16q+16)
  __shared__ float BC[64][128];   // per chunk: [t][B(64) | C(64)]
  __shared__ float xsL[64][16];
  __shared__ float dtL[64];
  __shared__ float dAL[64];
  float hs[16];
  #pragma unroll
  for (int i = 0; i < 16; ++i) hs[i] = 0.f;
  const float Dh = Dp[h];
  const int p0 = pg << 4;
  const long rowbase = (long)(b << 10);

  for (int t0 = 0; t0 < L_; t0 += 64) {
    __syncthreads();
    for (int i = lane; i < 64 * 32; i += 64) {          // BC stage (float4 units)
      int tt = i >> 5, c4 = (i & 31) << 2;
      *(float4*)&BC[tt][c4] =
          *(const float4*)&xc[(rowbase + t0 + tt) * CONVD + DI + c4];
    }
    for (int i = lane; i < 64 * 4; i += 64) {           // xs stage
      int tt = i >> 2, c4 = (i & 3) << 2;
      *(float4*)&xsL[tt][c4] =
          *(const float4*)&xc[(rowbase + t0 + tt) * CONVD + h * HD + p0 + c4];
    }
    {
      dtL[lane] = dts[(rowbase + t0 + lane) * NH + h];
      dAL[lane] = dAa[(rowbase + t0 + lane) * NH + h];
    }
    __syncthreads();
    for (int s = 0; s < 64; ++s) {
      const float dA = dAL[s];
      const float xv = xsL[s][pl];
      const float dtx = dtL[s] * xv;
      float yp = 0.f;
      const float* Br = &BC[s][q << 4];
      const float* Cr = &BC[s][64 + (q << 4)];
      #pragma unroll
      for (int j = 0; j < 4; ++j) {
        float4 b4 = *(const float4*)(Br + (j << 2));
        float4 c4 = *(const float4*)(Cr + (j << 2));
        const int k = j << 2;
        hs[k + 0] = fmaf(hs[k + 0], dA, dtx * b4.x); yp = fmaf(hs[k + 0], c4.x, yp);
        hs[k + 1] = fmaf(hs[k + 1], dA, dtx * b4.y); yp = fmaf(hs[k + 1], c4.y, yp);
        hs[k + 2] = fmaf(hs[k + 2], dA, dtx * b4.z); yp = fmaf(hs[k + 2], c4.z, yp);
        hs[k + 3] = fmaf(hs[k + 3], dA, dtx * b4.w); yp = fmaf(hs[k + 3], c4.w, yp);
      }
      yp += __shfl_xor(yp, 1, 64);
      yp += __shfl_xor(yp, 2, 64);
      if (q == 0)
        y[(rowbase + t0 + s) * DI + h * HD + p0 + pl] = fmaf(Dh, xv, yp);
    }
  }
}

// ---------------- gated rmsnorm: bf16( rms(y*silu(z)) * w ) ----------------
__global__ __launch_bounds__(256) void gated_rms_kernel(
    const float* __restrict__ y, const float* __restrict__ zx,
    const float* __restrict__ wt, u16* __restrict__ out) {
  const int row = blockIdx.x;
  const int c = threadIdx.x << 3;
  const float* yr = y + (long)row * DI + c;
  const float* zr = zx + (long)row * DPROJ + c;   // z = cols [0,2048)
  float v[8];
  float ss = 0.f;
  #pragma unroll
  for (int i = 0; i < 8; i += 4) {
    float4 y4 = *(const float4*)(yr + i);
    float4 z4 = *(const float4*)(zr + i);
    const float zz[4] = {z4.x, z4.y, z4.z, z4.w};
    const float yy[4] = {y4.x, y4.y, y4.z, y4.w};
    #pragma unroll
    for (int j = 0; j < 4; ++j) {
      float sg = zz[j] / (1.f + expf(-zz[j]));
      float val = yy[j] * sg;
      v[i + j] = val;
      ss += val * val;
    }
  }
  float tot = block_reduce_sum256(ss);
  float sc = rsqrtf(tot * (1.0f / DI) + 1e-5f);
  const float* wr = wt + c;
  *(ushort4*)(out + (long)row * DI + c) =
      make_ushort4(f2bf(v[0] * sc * wr[0]), f2bf(v[1] * sc * wr[1]),
                   f2bf(v[2] * sc * wr[2]), f2bf(v[3] * sc * wr[3]));
  *(ushort4*)(out + (long)row * DI + c + 4) =
      make_ushort4(f2bf(v[4] * sc * wr[4]), f2bf(v[5] * sc * wr[5]),
                   f2bf(v[6] * sc * wr[6]), f2bf(v[7] * sc * wr[7]));
}

// ---------------- final elementwise: MLP gate + both outputs ----------------
__global__ __launch_bounds__(256) void final_kernel(
    const float* __restrict__ xa, const float* __restrict__ g,
    const float* __restrict__ hh, const float* __restrict__ xd,
    const float* __restrict__ xf, float* __restrict__ out) {
  int i = blockIdx.x * 256 + threadIdx.x;   // float4 index over 2048*1024/4
  float4 g4 = ((const float4*)g)[i];
  float4 h4 = ((const float4*)hh)[i];
  float4 a4 = ((const float4*)xa)[i];
  float4 d4 = ((const float4*)xd)[i];
  float4 f4 = ((const float4*)xf)[i];
  float4 o0, o1;
  float sg;
  sg = g4.x / (1.f + expf(-g4.x)); float e0 = sg * h4.x;
  sg = g4.y / (1.f + expf(-g4.y)); float e1 = sg * h4.y;
  sg = g4.z / (1.f + expf(-g4.z)); float e2 = sg * h4.z;
  sg = g4.w / (1.f + expf(-g4.w)); float e3 = sg * h4.w;
  o0.x = a4.x + e0; o0.y = a4.y + e1; o0.z = a4.z + e2; o0.w = a4.w + e3;
  o1.x = d4.x + f4.x + e0; o1.y = d4.y + f4.y + e1;
  o1.z = d4.z + f4.z + e2; o1.w = d4.w + f4.w + e3;
  ((float4*)out)[i] = o0;
  ((float4*)(out + (long)B_ * L_ * DM))[i] = o1;
}

extern "C" void kernel_launch(void* const* d_in, const int* in_sizes, int n_in,
                              void* d_out, int out_size, void* d_ws, size_t ws_size,
                              hipStream_t stream) {
  const float* x        = (const float*)d_in[0];
  const float* x_d      = (const float*)d_in[1];
  const float* norm_w   = (const float*)d_in[2];
  const float* W_in     = (const float*)d_in[3];
  const float* conv_w   = (const float*)d_in[4];
  const float* conv_b   = (const float*)d_in[5];
  const float* dt_bias  = (const float*)d_in[6];
  const float* A_log    = (const float*)d_in[7];
  const float* D_param  = (const float*)d_in[8];
  const float* ssm_w    = (const float*)d_in[9];
  const float* W_out    = (const float*)d_in[10];
  const float* w1       = (const float*)d_in[11];
  const float* w2       = (const float*)d_in[12];
  float* out = (float*)d_out;

  char* wsc = (char*)d_ws;
  size_t off = 0;
  auto alloc = [&](size_t n) { char* p = wsc + off; off += (n + 255) & ~(size_t)255; return p; };
  float* zx   = (float*)alloc((size_t)2048 * 4256 * 4);
  float* xc   = (float*)alloc((size_t)2048 * 2176 * 4);
  float* yss  = (float*)alloc((size_t)2048 * 2048 * 4);
  float* xf   = (float*)alloc((size_t)2048 * 1024 * 4);
  float* xa   = (float*)alloc((size_t)2048 * 1024 * 4);
  float* gb   = (float*)alloc((size_t)2048 * 1024 * 4);
  float* hb   = (float*)alloc((size_t)2048 * 1024 * 4);
  float* dts  = (float*)alloc((size_t)65536 * 4);
  float* dAa  = (float*)alloc((size_t)65536 * 4);
  u16* xlnb   = (u16*)alloc((size_t)2048 * 1024 * 2);
  u16* ygnb   = (u16*)alloc((size_t)2048 * 2048 * 2);
  u16* xln2b  = (u16*)alloc((size_t)2048 * 1024 * 2);
  u16* Winb   = (u16*)alloc((size_t)4256 * 1024 * 2);
  u16* Woutb  = (u16*)alloc((size_t)1024 * 2048 * 2);
  u16* w1b    = (u16*)alloc((size_t)1024 * 1024 * 2);
  u16* w2b    = (u16*)alloc((size_t)1024 * 1024 * 2);

  // weight conversions
  f32_to_bf16<<<(4256 * 1024 / 4 + 255) / 256, 256, 0, stream>>>(W_in, Winb, 4256 * 1024 / 4);
  f32_to_bf16<<<(1024 * 2048 / 4 + 255) / 256, 256, 0, stream>>>(W_out, Woutb, 1024 * 2048 / 4);
  f32_to_bf16<<<(1024 * 1024 / 4 + 255) / 256, 256, 0, stream>>>(w1, w1b, 1024 * 1024 / 4);
  f32_to_bf16<<<(1024 * 1024 / 4 + 255) / 256, 256, 0, stream>>>(w2, w2b, 1024 * 1024 / 4);

  // 1) rmsnorm(x) -> bf16
  add_rms_kernel<<<2048, 256, 0, stream>>>(x, nullptr, nullptr, norm_w, xlnb, 1e-6f);
  // 2) in-proj
  gemm_bf16_nt<<<dim3(34, 16), 256, 0, stream>>>(xlnb, Winb, zx, 2048, 4256, 1024);
  // 3) dt/dA  and  conv+silu
  dtA_kernel<<<256, 256, 0, stream>>>(zx, dt_bias, A_log, dts, dAa);
  conv_silu_kernel<<<(2048 * 544 + 255) / 256, 256, 0, stream>>>(zx, conv_w, conv_b, xc);
  // 4) scan (+ D*x)
  scan_kernel<<<256, 64, 0, stream>>>(xc, dts, dAa, D_param, yss);
  // 5) gated rmsnorm -> bf16
  gated_rms_kernel<<<2048, 256, 0, stream>>>(yss, zx, ssm_w, ygnb);
  // 6) out-proj
  gemm_bf16_nt<<<dim3(8, 16), 256, 0, stream>>>(ygnb, Woutb, xf, 2048, 1024, 2048);
  // 7) x_a = x + x_f; rmsnorm -> bf16
  add_rms_kernel<<<2048, 256, 0, stream>>>(x, xf, xa, norm_w, xln2b, 1e-6f);
  // 8) MLP gemms
  gemm_bf16_nt<<<dim3(8, 16), 256, 0, stream>>>(xln2b, w1b, gb, 2048, 1024, 1024);
  gemm_bf16_nt<<<dim3(8, 16), 256, 0, stream>>>(xln2b, w2b, hb, 2048, 1024, 1024);
  // 9) outputs
  final_kernel<<<2048, 256, 0, stream>>>(xa, gb, hb, x_d, xf, out);
}

// Round 2
// 505.301 us; speedup vs baseline: 1.7009x; 1.7009x over previous
//
#include <hip/hip_runtime.h>

typedef unsigned short u16;
typedef __attribute__((ext_vector_type(8))) short bf16x8;
typedef __attribute__((ext_vector_type(4))) float f32x4;

#define B_      2
#define L_      1024
#define DM      1024
#define DI      2048
#define NH      32
#define HD      64
#define DSTATE  64
#define CONVD   2176
#define DPROJ   4256

__device__ __forceinline__ u16 f2bf(float f) {
  union { float f; unsigned u; } v; v.f = f;
  unsigned r = v.u + 0x7fffu + ((v.u >> 16) & 1u);   // RNE
  return (u16)(r >> 16);
}

__device__ __forceinline__ float block_reduce_sum256(float v) {
  #pragma unroll
  for (int off = 32; off > 0; off >>= 1) v += __shfl_down(v, off, 64);
  __shared__ float red[4];
  int lane = threadIdx.x & 63, w = threadIdx.x >> 6;
  if (lane == 0) red[w] = v;
  __syncthreads();
  return red[0] + red[1] + red[2] + red[3];
}

// ---------------- f32 -> bf16 convert ----------------
__global__ __launch_bounds__(256) void f32_to_bf16(const float* __restrict__ in,
                                                   u16* __restrict__ out, int n4) {
  int i = blockIdx.x * 256 + threadIdx.x;
  if (i < n4) {
    float4 v = ((const float4*)in)[i];
    ((ushort4*)out)[i] = make_ushort4(f2bf(v.x), f2bf(v.y), f2bf(v.z), f2bf(v.w));
  }
}

// ---------------- rmsnorm (optionally fused residual add) ----------------
__global__ __launch_bounds__(256) void add_rms_kernel(
    const float* __restrict__ in1, const float* __restrict__ in2,
    float* __restrict__ sum_out, const float* __restrict__ wt,
    u16* __restrict__ out, float eps) {
  const int row = blockIdx.x;
  const int c = threadIdx.x << 2;
  float4 v = *(const float4*)(in1 + (long)row * DM + c);
  if (in2) {
    float4 u = *(const float4*)(in2 + (long)row * DM + c);
    v.x += u.x; v.y += u.y; v.z += u.z; v.w += u.w;
  }
  if (sum_out) *(float4*)(sum_out + (long)row * DM + c) = v;
  float ss = v.x * v.x + v.y * v.y + v.z * v.z + v.w * v.w;
  float tot = block_reduce_sum256(ss);
  float sc = rsqrtf(tot * (1.0f / DM) + eps);
  float4 wv = *(const float4*)(wt + c);
  *(ushort4*)(out + (long)row * DM + c) =
      make_ushort4(f2bf(v.x * sc * wv.x), f2bf(v.y * sc * wv.y),
                   f2bf(v.z * sc * wv.z), f2bf(v.w * sc * wv.w));
}

// ---------------- bf16 NT GEMM: C[m,n] = sum_k A[m,k]*Bw[n,k] ----------------
__global__ __launch_bounds__(256) void gemm_bf16_nt(
    const u16* __restrict__ A, const u16* __restrict__ Bw,
    float* __restrict__ C, int M, int N, int K) {
  __shared__ u16 As[128][72];
  __shared__ u16 Bs[128][72];
  const int tid = threadIdx.x;
  const int lane = tid & 63;
  const int wave = tid >> 6;
  const int wm = (wave & 1) << 6;
  const int wn = (wave >> 1) << 6;
  const int bm = blockIdx.y << 7;
  const int bn = blockIdx.x << 7;
  const int lrow = tid >> 3;
  const int lcol = (tid & 7) << 3;

  f32x4 acc[4][4];
  #pragma unroll
  for (int i = 0; i < 4; ++i)
    #pragma unroll
    for (int j = 0; j < 4; ++j)
      acc[i][j] = (f32x4){0.f, 0.f, 0.f, 0.f};

  const u16* Aptr = A + (long)(bm + lrow) * K + lcol;
  const u16* Bptr = Bw + (long)(bn + lrow) * K + lcol;

  uint4 ar[4], br[4];
  const uint4 z4 = make_uint4(0, 0, 0, 0);
  #pragma unroll
  for (int p = 0; p < 4; ++p) {
    ar[p] = *(const uint4*)(Aptr + (long)p * 32 * K);
    br[p] = (bn + lrow + p * 32 < N) ? *(const uint4*)(Bptr + (long)p * 32 * K) : z4;
  }

  for (int kt = 0; kt < K; kt += 64) {
    __syncthreads();
    #pragma unroll
    for (int p = 0; p < 4; ++p) {
      *(uint4*)&As[lrow + p * 32][lcol] = ar[p];
      *(uint4*)&Bs[lrow + p * 32][lcol] = br[p];
    }
    __syncthreads();
    if (kt + 64 < K) {
      #pragma unroll
      for (int p = 0; p < 4; ++p) {
        ar[p] = *(const uint4*)(Aptr + (kt + 64) + (long)p * 32 * K);
        br[p] = (bn + lrow + p * 32 < N) ? *(const uint4*)(Bptr + (kt + 64) + (long)p * 32 * K) : z4;
      }
    }
    #pragma unroll
    for (int ks = 0; ks < 2; ++ks) {
      const int krow = (ks << 5) + ((lane >> 4) << 3);
      bf16x8 af[4], bf[4];
      #pragma unroll
      for (int i = 0; i < 4; ++i)
        af[i] = *(const bf16x8*)&As[wm + (i << 4) + (lane & 15)][krow];
      #pragma unroll
      for (int j = 0; j < 4; ++j)
        bf[j] = *(const bf16x8*)&Bs[wn + (j << 4) + (lane & 15)][krow];
      #pragma unroll
      for (int i = 0; i < 4; ++i)
        #pragma unroll
        for (int j = 0; j < 4; ++j)
          acc[i][j] = __builtin_amdgcn_mfma_f32_16x16x32_bf16(af[i], bf[j], acc[i][j], 0, 0, 0);
    }
  }

  const int col = lane & 15;
  const int rquad = (lane >> 4) << 2;
  #pragma unroll
  for (int i = 0; i < 4; ++i) {
    const int gm = bm + wm + (i << 4) + rquad;
    #pragma unroll
    for (int j = 0; j < 4; ++j) {
      const int gn = bn + wn + (j << 4) + col;
      if (gn < N) {
        #pragma unroll
        for (int r = 0; r < 4; ++r)
          C[(long)(gm + r) * N + gn] = acc[i][j][r];
      }
    }
  }
}

// ---------------- dt softplus + log-decay ----------------
__global__ __launch_bounds__(256) void dtA_kernel(
    const float* __restrict__ zx, const float* __restrict__ dt_bias,
    const float* __restrict__ A_log, float* __restrict__ dts,
    float* __restrict__ glog) {
  int idx = blockIdx.x * 256 + threadIdx.x;   // B_*L_*NH = 65536
  int h = idx & (NH - 1);
  int row = idx >> 5;
  float x = zx[(long)row * DPROJ + (DI + CONVD) + h] + dt_bias[h];
  float sp = (x > 20.f) ? x : log1pf(expf(x));
  dts[idx] = sp;
  glog[idx] = -expf(A_log[h]) * sp;   // log(dA), exact
}

// ---------------- depthwise causal conv (k=4) + silu ----------------
__global__ __launch_bounds__(256) void conv_silu_kernel(
    const float* __restrict__ zx, const float* __restrict__ cw,
    const float* __restrict__ cb, float* __restrict__ xc) {
  int idx = blockIdx.x * 256 + threadIdx.x;
  if (idx >= 2048 * 544) return;
  const int c4 = (idx % 544) << 2;
  const int row = idx / 544;
  const int t = row & (L_ - 1);
  float4 acc = *(const float4*)(cb + c4);
  float4 w0 = *(const float4*)(cw + (c4 + 0) * 4);
  float4 w1v = *(const float4*)(cw + (c4 + 1) * 4);
  float4 w2v = *(const float4*)(cw + (c4 + 2) * 4);
  float4 w3v = *(const float4*)(cw + (c4 + 3) * 4);
  const float wts[4][4] = {{w0.x, w0.y, w0.z, w0.w},
                           {w1v.x, w1v.y, w1v.z, w1v.w},
                           {w2v.x, w2v.y, w2v.z, w2v.w},
                           {w3v.x, w3v.y, w3v.z, w3v.w}};
  #pragma unroll
  for (int i = 0; i < 4; ++i) {
    int tau = t - 3 + i;
    if (tau >= 0) {
      float4 xv = *(const float4*)(zx + (long)(row - t + tau) * DPROJ + DI + c4);
      acc.x = fmaf(xv.x, wts[0][i], acc.x);
      acc.y = fmaf(xv.y, wts[1][i], acc.y);
      acc.z = fmaf(xv.z, wts[2][i], acc.z);
      acc.w = fmaf(xv.w, wts[3][i], acc.w);
    }
  }
  acc.x = acc.x / (1.f + expf(-acc.x));
  acc.y = acc.y / (1.f + expf(-acc.y));
  acc.z = acc.z / (1.f + expf(-acc.z));
  acc.w = acc.w / (1.f + expf(-acc.w));
  *(float4*)(xc + (long)row * CONVD + c4) = acc;
}

// ================= chunked SSD scan =================
// S1: per (b,h,chunk): Y_intra = M@X, S^T[p][n] = sum_j X^T[p][j]*(B[j][n]*w_j)
__global__ __launch_bounds__(256) void ssd_chunk_kernel(
    const float* __restrict__ xc, const float* __restrict__ dts,
    const float* __restrict__ glog, float* __restrict__ yss,
    float* __restrict__ Sbuf, float* __restrict__ EGbuf,
    float* __restrict__ Lam) {
  const int c = blockIdx.x & 15;
  const int h = (blockIdx.x >> 4) & 31;
  const int b = blockIdx.x >> 9;
  const int bh = b * NH + h;
  const long crow = (long)b * L_ + c * 64;
  const int tid = threadIdx.x, lane = tid & 63, wave = tid >> 6;

  __shared__ u16 Cs[64][72], Bs[64][72], Xt[64][72], Btw[64][72], Ms[64][72];
  __shared__ float Gs[64], wjL[64], dtL[64];

  if (wave == 0) {
    float g = glog[(crow + lane) * NH + h];
    float dt = dts[(crow + lane) * NH + h];
    float G = g;
    #pragma unroll
    for (int off = 1; off < 64; off <<= 1) {
      float t = __shfl_up(G, off, 64);
      if (lane >= off) G += t;
    }
    float G63 = __shfl(G, 63, 64);
    Gs[lane] = G;
    wjL[lane] = expf(G63 - G) * dt;
    dtL[lane] = dt;
    EGbuf[(bh * 16 + c) * 64 + lane] = expf(G);
    if (lane == 63) Lam[bh * 16 + c] = expf(G63);
  }
  __syncthreads();
  // stage X^T, B, B^T*w, C (f32 -> bf16)
  for (int idx = tid; idx < 1024; idx += 256) {
    int r = idx >> 4, c4 = (idx & 15) << 2;
    const float* row = xc + (crow + r) * CONVD;
    float4 xv = *(const float4*)(row + h * HD + c4);
    Xt[c4 + 0][r] = f2bf(xv.x); Xt[c4 + 1][r] = f2bf(xv.y);
    Xt[c4 + 2][r] = f2bf(xv.z); Xt[c4 + 3][r] = f2bf(xv.w);
    float4 bv = *(const float4*)(row + DI + c4);
    *(ushort4*)&Bs[r][c4] = make_ushort4(f2bf(bv.x), f2bf(bv.y), f2bf(bv.z), f2bf(bv.w));
    float w = wjL[r];
    Btw[c4 + 0][r] = f2bf(bv.x * w); Btw[c4 + 1][r] = f2bf(bv.y * w);
    Btw[c4 + 2][r] = f2bf(bv.z * w); Btw[c4 + 3][r] = f2bf(bv.w * w);
    float4 cv = *(const float4*)(row + DI + DSTATE + c4);
    *(ushort4*)&Cs[r][c4] = make_ushort4(f2bf(cv.x), f2bf(cv.y), f2bf(cv.z), f2bf(cv.w));
  }
  __syncthreads();

  const int mrow = wave * 16 + (lane & 15);
  const int quad = lane >> 4;
  // GEMM1: E = C B^T
  f32x4 accE[4];
  #pragma unroll
  for (int j = 0; j < 4; ++j) accE[j] = (f32x4){0.f, 0.f, 0.f, 0.f};
  #pragma unroll
  for (int ks = 0; ks < 2; ++ks) {
    int k0 = ks * 32 + quad * 8;
    bf16x8 a = *(const bf16x8*)&Cs[mrow][k0];
    #pragma unroll
    for (int j = 0; j < 4; ++j) {
      bf16x8 bfr = *(const bf16x8*)&Bs[j * 16 + (lane & 15)][k0];
      accE[j] = __builtin_amdgcn_mfma_f32_16x16x32_bf16(a, bfr, accE[j], 0, 0, 0);
    }
  }
  // epilogue: mask + scale -> Ms (bf16)
  #pragma unroll
  for (int j = 0; j < 4; ++j) {
    int jc = j * 16 + (lane & 15);
    float Gj = Gs[jc], dtj = dtL[jc];
    #pragma unroll
    for (int r = 0; r < 4; ++r) {
      int ir = wave * 16 + quad * 4 + r;
      float v = (ir >= jc) ? accE[j][r] * expf(Gs[ir] - Gj) * dtj : 0.f;
      Ms[ir][jc] = f2bf(v);
    }
  }
  __syncthreads();
  // GEMM2: Yintra = M @ X ; GEMM3: S^T = X^T @ (B w)^T
  f32x4 accY[4], accS[4];
  #pragma unroll
  for (int j = 0; j < 4; ++j) { accY[j] = (f32x4){0.f,0.f,0.f,0.f}; accS[j] = (f32x4){0.f,0.f,0.f,0.f}; }
  #pragma unroll
  for (int ks = 0; ks < 2; ++ks) {
    int k0 = ks * 32 + quad * 8;
    bf16x8 aM = *(const bf16x8*)&Ms[mrow][k0];
    bf16x8 aX = *(const bf16x8*)&Xt[mrow][k0];
    #pragma unroll
    for (int j = 0; j < 4; ++j) {
      bf16x8 bX = *(const bf16x8*)&Xt[j * 16 + (lane & 15)][k0];
      bf16x8 bB = *(const bf16x8*)&Btw[j * 16 + (lane & 15)][k0];
      accY[j] = __builtin_amdgcn_mfma_f32_16x16x32_bf16(aM, bX, accY[j], 0, 0, 0);
      accS[j] = __builtin_amdgcn_mfma_f32_16x16x32_bf16(aX, bB, accS[j], 0, 0, 0);
    }
  }
  float* Sc = Sbuf + (long)(bh * 16 + c) * 4096;
  #pragma unroll
  for (int j = 0; j < 4; ++j) {
    int col = j * 16 + (lane & 15);
    #pragma unroll
    for (int r = 0; r < 4; ++r) {
      int mr = wave * 16 + quad * 4 + r;
      yss[(crow + mr) * DI + h * HD + col] = accY[j][r];   // Y_intra[i=mr][p=col]
      Sc[mr * 64 + col] = accS[j][r];                      // S^T[p=mr][n=col]
    }
  }
}

// S2: serial combine over chunks; Sbuf[c] becomes carry-in H for chunk c
__global__ __launch_bounds__(256) void ssd_combine_kernel(
    float* __restrict__ Sbuf, const float* __restrict__ Lam) {
  const int bh = blockIdx.x;
  float* base = Sbuf + (long)bh * 16 * 4096 + threadIdx.x * 16;
  float H[16];
  #pragma unroll
  for (int k = 0; k < 16; ++k) H[k] = 0.f;
  for (int cc = 0; cc < 16; ++cc) {
    float lam = Lam[bh * 16 + cc];
    float* p = base + cc * 4096;
    float tmp[16];
    #pragma unroll
    for (int k = 0; k < 16; k += 4) {
      float4 v = *(const float4*)(p + k);
      tmp[k] = v.x; tmp[k + 1] = v.y; tmp[k + 2] = v.z; tmp[k + 3] = v.w;
    }
    #pragma unroll
    for (int k = 0; k < 16; k += 4)
      *(float4*)(p + k) = make_float4(H[k], H[k + 1], H[k + 2], H[k + 3]);
    #pragma unroll
    for (int k = 0; k < 16; ++k) H[k] = fmaf(lam, H[k], tmp[k]);
  }
}

// S3: Y += exp(G_i) * C_i . H_in + D*x
__global__ __launch_bounds__(256) void ssd_final_kernel(
    const float* __restrict__ xc, const float* __restrict__ Sbuf,
    const float* __restrict__ EGbuf, const float* __restrict__ Dp,
    float* __restrict__ yss) {
  const int c = blockIdx.x & 15;
  const int h = (blockIdx.x >> 4) & 31;
  const int b = blockIdx.x >> 9;
  const int bh = b * NH + h;
  const long crow = (long)b * L_ + c * 64;
  const int tid = threadIdx.x, lane = tid & 63, wave = tid >> 6;
  __shared__ u16 Csc[64][72], Hs[64][72];
  __shared__ float egL[64];
  if (tid < 64) egL[tid] = EGbuf[(bh * 16 + c) * 64 + tid];
  __syncthreads();
  const float* Sc = Sbuf + (long)(bh * 16 + c) * 4096;
  for (int idx = tid; idx < 1024; idx += 256) {
    int r = idx >> 4, c4 = (idx & 15) << 2;
    float4 hv = *(const float4*)(Sc + r * 64 + c4);
    *(ushort4*)&Hs[r][c4] = make_ushort4(f2bf(hv.x), f2bf(hv.y), f2bf(hv.z), f2bf(hv.w));
    float eg = egL[r];
    float4 cv = *(const float4*)(xc + (crow + r) * CONVD + DI + DSTATE + c4);
    *(ushort4*)&Csc[r][c4] = make_ushort4(f2bf(cv.x * eg), f2bf(cv.y * eg),
                                          f2bf(cv.z * eg), f2bf(cv.w * eg));
  }
  __syncthreads();
  const int mrow = wave * 16 + (lane & 15);
  const int quad = lane >> 4;
  f32x4 acc[4];
  #pragma unroll
  for (int j = 0; j < 4; ++j) acc[j] = (f32x4){0.f, 0.f, 0.f, 0.f};
  #pragma unroll
  for (int ks = 0; ks < 2; ++ks) {
    int k0 = ks * 32 + quad * 8;
    bf16x8 a = *(const bf16x8*)&Csc[mrow][k0];
    #pragma unroll
    for (int j = 0; j < 4; ++j) {
      bf16x8 bfr = *(const bf16x8*)&Hs[j * 16 + (lane & 15)][k0];
      acc[j] = __builtin_amdgcn_mfma_f32_16x16x32_bf16(a, bfr, acc[j], 0, 0, 0);
    }
  }
  const float Dh = Dp[h];
  #pragma unroll
  for (int j = 0; j < 4; ++j) {
    int p = j * 16 + (lane & 15);
    #pragma unroll
    for (int r = 0; r < 4; ++r) {
      int ir = wave * 16 + quad * 4 + r;
      long o = (crow + ir) * DI + h * HD + p;
      float xval = xc[(crow + ir) * CONVD + h * HD + p];
      yss[o] = yss[o] + acc[j][r] + Dh * xval;
    }
  }
}

// ---------------- gated rmsnorm: bf16( rms(y*silu(z)) * w ) ----------------
__global__ __launch_bounds__(256) void gated_rms_kernel(
    const float* __restrict__ y, const float* __restrict__ zx,
    const float* __restrict__ wt, u16* __restrict__ out) {
  const int row = blockIdx.x;
  const int c = threadIdx.x << 3;
  const float* yr = y + (long)row * DI + c;
  const float* zr = zx + (long)row * DPROJ + c;
  float v[8];
  float ss = 0.f;
  #pragma unroll
  for (int i = 0; i < 8; i += 4) {
    float4 y4 = *(const float4*)(yr + i);
    float4 z4 = *(const float4*)(zr + i);
    const float zz[4] = {z4.x, z4.y, z4.z, z4.w};
    const float yy[4] = {y4.x, y4.y, y4.z, y4.w};
    #pragma unroll
    for (int j = 0; j < 4; ++j) {
      float sg = zz[j] / (1.f + expf(-zz[j]));
      float val = yy[j] * sg;
      v[i + j] = val;
      ss += val * val;
    }
  }
  float tot = block_reduce_sum256(ss);
  float sc = rsqrtf(tot * (1.0f / DI) + 1e-5f);
  const float* wr = wt + c;
  *(ushort4*)(out + (long)row * DI + c) =
      make_ushort4(f2bf(v[0] * sc * wr[0]), f2bf(v[1] * sc * wr[1]),
                   f2bf(v[2] * sc * wr[2]), f2bf(v[3] * sc * wr[3]));
  *(ushort4*)(out + (long)row * DI + c + 4) =
      make_ushort4(f2bf(v[4] * sc * wr[4]), f2bf(v[5] * sc * wr[5]),
                   f2bf(v[6] * sc * wr[6]), f2bf(v[7] * sc * wr[7]));
}

// ---------------- final elementwise ----------------
__global__ __launch_bounds__(256) void final_kernel(
    const float* __restrict__ xa, const float* __restrict__ g,
    const float* __restrict__ hh, const float* __restrict__ xd,
    const float* __restrict__ xf, float* __restrict__ out) {
  int i = blockIdx.x * 256 + threadIdx.x;
  float4 g4 = ((const float4*)g)[i];
  float4 h4 = ((const float4*)hh)[i];
  float4 a4 = ((const float4*)xa)[i];
  float4 d4 = ((const float4*)xd)[i];
  float4 f4 = ((const float4*)xf)[i];
  float4 o0, o1;
  float sg;
  sg = g4.x / (1.f + expf(-g4.x)); float e0 = sg * h4.x;
  sg = g4.y / (1.f + expf(-g4.y)); float e1 = sg * h4.y;
  sg = g4.z / (1.f + expf(-g4.z)); float e2 = sg * h4.z;
  sg = g4.w / (1.f + expf(-g4.w)); float e3 = sg * h4.w;
  o0.x = a4.x + e0; o0.y = a4.y + e1; o0.z = a4.z + e2; o0.w = a4.w + e3;
  o1.x = d4.x + f4.x + e0; o1.y = d4.y + f4.y + e1;
  o1.z = d4.z + f4.z + e2; o1.w = d4.w + f4.w + e3;
  ((float4*)out)[i] = o0;
  ((float4*)(out + (long)B_ * L_ * DM))[i] = o1;
}

extern "C" void kernel_launch(void* const* d_in, const int* in_sizes, int n_in,
                              void* d_out, int out_size, void* d_ws, size_t ws_size,
                              hipStream_t stream) {
  const float* x        = (const float*)d_in[0];
  const float* x_d      = (const float*)d_in[1];
  const float* norm_w   = (const float*)d_in[2];
  const float* W_in     = (const float*)d_in[3];
  const float* conv_w   = (const float*)d_in[4];
  const float* conv_b   = (const float*)d_in[5];
  const float* dt_bias  = (const float*)d_in[6];
  const float* A_log    = (const float*)d_in[7];
  const float* D_param  = (const float*)d_in[8];
  const float* ssm_w    = (const float*)d_in[9];
  const float* W_out    = (const float*)d_in[10];
  const float* w1       = (const float*)d_in[11];
  const float* w2       = (const float*)d_in[12];
  float* out = (float*)d_out;

  char* wsc = (char*)d_ws;
  size_t off = 0;
  auto alloc = [&](size_t n) { char* p = wsc + off; off += (n + 255) & ~(size_t)255; return p; };
  float* zx   = (float*)alloc((size_t)2048 * 4256 * 4);
  float* xc   = (float*)alloc((size_t)2048 * 2176 * 4);
  float* yss  = (float*)alloc((size_t)2048 * 2048 * 4);
  float* xf   = (float*)alloc((size_t)2048 * 1024 * 4);
  float* xa   = (float*)alloc((size_t)2048 * 1024 * 4);
  float* gb   = (float*)alloc((size_t)2048 * 1024 * 4);
  float* hb   = (float*)alloc((size_t)2048 * 1024 * 4);
  float* dts  = (float*)alloc((size_t)65536 * 4);
  float* glog = (float*)alloc((size_t)65536 * 4);
  float* EGbuf= (float*)alloc((size_t)65536 * 4);
  float* Lam  = (float*)alloc((size_t)1024 * 4);
  u16* xlnb   = (u16*)alloc((size_t)2048 * 1024 * 2);
  u16* ygnb   = (u16*)alloc((size_t)2048 * 2048 * 2);
  u16* xln2b  = (u16*)alloc((size_t)2048 * 1024 * 2);
  u16* Winb   = (u16*)alloc((size_t)4256 * 1024 * 2);
  u16* Woutb  = (u16*)alloc((size_t)1024 * 2048 * 2);
  u16* w1b    = (u16*)alloc((size_t)1024 * 1024 * 2);
  u16* w2b    = (u16*)alloc((size_t)1024 * 1024 * 2);
  // Sbuf (16 MB) aliases gb+hb (contiguous 16 MB): scan finishes before MLP GEMMs write gb/hb
  float* Sbuf = gb;

  f32_to_bf16<<<(4256 * 1024 / 4 + 255) / 256, 256, 0, stream>>>(W_in, Winb, 4256 * 1024 / 4);
  f32_to_bf16<<<(1024 * 2048 / 4 + 255) / 256, 256, 0, stream>>>(W_out, Woutb, 1024 * 2048 / 4);
  f32_to_bf16<<<(1024 * 1024 / 4 + 255) / 256, 256, 0, stream>>>(w1, w1b, 1024 * 1024 / 4);
  f32_to_bf16<<<(1024 * 1024 / 4 + 255) / 256, 256, 0, stream>>>(w2, w2b, 1024 * 1024 / 4);

  add_rms_kernel<<<2048, 256, 0, stream>>>(x, nullptr, nullptr, norm_w, xlnb, 1e-6f);
  gemm_bf16_nt<<<dim3(34, 16), 256, 0, stream>>>(xlnb, Winb, zx, 2048, 4256, 1024);
  dtA_kernel<<<256, 256, 0, stream>>>(zx, dt_bias, A_log, dts, glog);
  conv_silu_kernel<<<(2048 * 544 + 255) / 256, 256, 0, stream>>>(zx, conv_w, conv_b, xc);
  // chunked SSD scan
  ssd_chunk_kernel<<<1024, 256, 0, stream>>>(xc, dts, glog, yss, Sbuf, EGbuf, Lam);
  ssd_combine_kernel<<<64, 256, 0, stream>>>(Sbuf, Lam);
  ssd_final_kernel<<<1024, 256, 0, stream>>>(xc, Sbuf, EGbuf, D_param, yss);

  gated_rms_kernel<<<2048, 256, 0, stream>>>(yss, zx, ssm_w, ygnb);
  gemm_bf16_nt<<<dim3(8, 16), 256, 0, stream>>>(ygnb, Woutb, xf, 2048, 1024, 2048);
  add_rms_kernel<<<2048, 256, 0, stream>>>(x, xf, xa, norm_w, xln2b, 1e-6f);
  gemm_bf16_nt<<<dim3(8, 16), 256, 0, stream>>>(xln2b, w1b, gb, 2048, 1024, 1024);
  gemm_bf16_nt<<<dim3(8, 16), 256, 0, stream>>>(xln2b, w2b, hb, 2048, 1024, 1024);
  final_kernel<<<2048, 256, 0, stream>>>(xa, gb, hb, x_d, xf, out);
}

// Round 3
// 305.226 us; speedup vs baseline: 2.8158x; 1.6555x over previous
//
#include <hip/hip_runtime.h>

typedef unsigned short u16;
typedef __attribute__((ext_vector_type(8))) short bf16x8;
typedef __attribute__((ext_vector_type(4))) float f32x4;

#define B_      2
#define L_      1024
#define DM      1024
#define DI      2048
#define NH      32
#define HD      64
#define DSTATE  64
#define CONVD   2176
#define DPROJ   4256
#define ZXS     4352   // padded zx row stride (34*128)

__device__ __forceinline__ u16 f2bf(float f) {
  union { float f; unsigned u; } v; v.f = f;
  unsigned r = v.u + 0x7fffu + ((v.u >> 16) & 1u);   // RNE
  return (u16)(r >> 16);
}

__device__ __forceinline__ void load_lds16(const void* g, void* l) {
  __builtin_amdgcn_global_load_lds(
      (const __attribute__((address_space(1))) void*)g,
      (__attribute__((address_space(3))) void*)l, 16, 0, 0);
}

__device__ __forceinline__ float block_reduce_sum256(float v) {
  #pragma unroll
  for (int off = 32; off > 0; off >>= 1) v += __shfl_down(v, off, 64);
  __shared__ float red[4];
  int lane = threadIdx.x & 63, w = threadIdx.x >> 6;
  if (lane == 0) red[w] = v;
  __syncthreads();
  return red[0] + red[1] + red[2] + red[3];
}

// ---------------- f32 -> bf16 convert ----------------
__global__ __launch_bounds__(256) void f32_to_bf16(const float* __restrict__ in,
                                                   u16* __restrict__ out, int n4) {
  int i = blockIdx.x * 256 + threadIdx.x;
  if (i < n4) {
    float4 v = ((const float4*)in)[i];
    ((ushort4*)out)[i] = make_ushort4(f2bf(v.x), f2bf(v.y), f2bf(v.z), f2bf(v.w));
  }
}

// ---------------- rmsnorm (optionally fused residual add) ----------------
__global__ __launch_bounds__(256) void add_rms_kernel(
    const float* __restrict__ in1, const float* __restrict__ in2,
    float* __restrict__ sum_out, const float* __restrict__ wt,
    u16* __restrict__ out, float eps) {
  const int row = blockIdx.x;
  const int c = threadIdx.x << 2;
  float4 v = *(const float4*)(in1 + (long)row * DM + c);
  if (in2) {
    float4 u = *(const float4*)(in2 + (long)row * DM + c);
    v.x += u.x; v.y += u.y; v.z += u.z; v.w += u.w;
  }
  if (sum_out) *(float4*)(sum_out + (long)row * DM + c) = v;
  float ss = v.x * v.x + v.y * v.y + v.z * v.z + v.w * v.w;
  float tot = block_reduce_sum256(ss);
  float sc = rsqrtf(tot * (1.0f / DM) + eps);
  float4 wv = *(const float4*)(wt + c);
  *(ushort4*)(out + (long)row * DM + c) =
      make_ushort4(f2bf(v.x * sc * wv.x), f2bf(v.y * sc * wv.y),
                   f2bf(v.z * sc * wv.z), f2bf(v.w * sc * wv.w));
}

// ---------------- bf16 NT GEMM with global_load_lds + XOR swizzle ----------------
// C[m,n] = sum_k A[m,k]*Bw[n,k]. Tile 128 x (NJ*32), BK=64, 256 threads.
// LDS layout: As[row][ (chunk ^ (row&7))*8 .. ] holds logical A[row][chunk*8..]
template<int NJ>
__global__ __launch_bounds__(256) void gemm_lds(
    const u16* __restrict__ A, const u16* __restrict__ Bw,
    float* __restrict__ C, int N, int Nw, int K) {
  constexpr int BN = NJ * 32;
  __shared__ u16 As[128][64];
  __shared__ u16 Bs[BN][64];
  const int tid = threadIdx.x;
  const int lane = tid & 63;
  const int wave = tid >> 6;
  const int ml = lane & 15;
  const int quad = lane >> 4;
  const int wm = (wave & 1) << 6;
  const int wn = (wave >> 1) * (BN / 2);
  const long bm = (long)blockIdx.y << 7;
  const long bn = (long)blockIdx.x * BN;

  // staging lane map: lane -> (row lr in unit, swizzled 16B chunk lc)
  const int lr = lane >> 3;
  const int lc = (lane & 7) ^ lr;

  f32x4 acc[4][NJ];
  #pragma unroll
  for (int i = 0; i < 4; ++i)
    #pragma unroll
    for (int j = 0; j < NJ; ++j)
      acc[i][j] = (f32x4){0.f, 0.f, 0.f, 0.f};

  auto stage = [&](int kk) {
    #pragma unroll
    for (int t = 0; t < 4; ++t) {
      const int u = wave * 4 + t;
      const u16* g = A + (bm + u * 8 + lr) * K + kk + lc * 8;
      load_lds16(g, &As[u * 8][0]);
    }
    #pragma unroll
    for (int t = 0; t < NJ; ++t) {
      const int u = wave * NJ + t;
      long brow = bn + u * 8 + lr;
      if (brow >= Nw) brow = Nw - 1;
      const u16* g = Bw + brow * K + kk + lc * 8;
      load_lds16(g, &Bs[u * 8][0]);
    }
  };

  stage(0);
  for (int kt = 0; kt < K; kt += 64) {
    __syncthreads();   // drains vmcnt -> LDS tile visible
    #pragma unroll
    for (int ks = 0; ks < 2; ++ks) {
      const int c = ks * 4 + quad;
      const int pc = (c ^ (ml & 7)) << 3;
      bf16x8 af[4], bfr[NJ];
      #pragma unroll
      for (int i = 0; i < 4; ++i)
        af[i] = *(const bf16x8*)&As[wm + (i << 4) + ml][pc];
      #pragma unroll
      for (int j = 0; j < NJ; ++j)
        bfr[j] = *(const bf16x8*)&Bs[wn + (j << 4) + ml][pc];
      #pragma unroll
      for (int i = 0; i < 4; ++i)
        #pragma unroll
        for (int j = 0; j < NJ; ++j)
          acc[i][j] = __builtin_amdgcn_mfma_f32_16x16x32_bf16(af[i], bfr[j], acc[i][j], 0, 0, 0);
    }
    if (kt + 64 < K) {
      __syncthreads();   // LDS reuse WAR
      stage(kt + 64);
    }
  }

  const int rquad = quad << 2;
  #pragma unroll
  for (int i = 0; i < 4; ++i) {
    const long gm = bm + wm + (i << 4) + rquad;
    #pragma unroll
    for (int j = 0; j < NJ; ++j) {
      const long gn = bn + wn + (j << 4) + ml;
      #pragma unroll
      for (int r = 0; r < 4; ++r)
        C[(gm + r) * N + gn] = acc[i][j][r];
    }
  }
}

// ---------------- dt softplus + log-decay ----------------
__global__ __launch_bounds__(256) void dtA_kernel(
    const float* __restrict__ zx, const float* __restrict__ dt_bias,
    const float* __restrict__ A_log, float* __restrict__ dts,
    float* __restrict__ glog) {
  int idx = blockIdx.x * 256 + threadIdx.x;   // B_*L_*NH = 65536
  int h = idx & (NH - 1);
  int row = idx >> 5;
  float x = zx[(long)row * ZXS + (DI + CONVD) + h] + dt_bias[h];
  float sp = (x > 20.f) ? x : log1pf(expf(x));
  dts[idx] = sp;
  glog[idx] = -expf(A_log[h]) * sp;   // log(dA), exact
}

// ---------------- depthwise causal conv (k=4) + silu ----------------
__global__ __launch_bounds__(256) void conv_silu_kernel(
    const float* __restrict__ zx, const float* __restrict__ cw,
    const float* __restrict__ cb, float* __restrict__ xc) {
  int idx = blockIdx.x * 256 + threadIdx.x;
  if (idx >= 2048 * 544) return;
  const int c4 = (idx % 544) << 2;
  const int row = idx / 544;
  const int t = row & (L_ - 1);
  float4 acc = *(const float4*)(cb + c4);
  float4 w0 = *(const float4*)(cw + (c4 + 0) * 4);
  float4 w1v = *(const float4*)(cw + (c4 + 1) * 4);
  float4 w2v = *(const float4*)(cw + (c4 + 2) * 4);
  float4 w3v = *(const float4*)(cw + (c4 + 3) * 4);
  const float wts[4][4] = {{w0.x, w0.y, w0.z, w0.w},
                           {w1v.x, w1v.y, w1v.z, w1v.w},
                           {w2v.x, w2v.y, w2v.z, w2v.w},
                           {w3v.x, w3v.y, w3v.z, w3v.w}};
  #pragma unroll
  for (int i = 0; i < 4; ++i) {
    int tau = t - 3 + i;
    if (tau >= 0) {
      float4 xv = *(const float4*)(zx + (long)(row - t + tau) * ZXS + DI + c4);
      acc.x = fmaf(xv.x, wts[0][i], acc.x);
      acc.y = fmaf(xv.y, wts[1][i], acc.y);
      acc.z = fmaf(xv.z, wts[2][i], acc.z);
      acc.w = fmaf(xv.w, wts[3][i], acc.w);
    }
  }
  acc.x = acc.x / (1.f + expf(-acc.x));
  acc.y = acc.y / (1.f + expf(-acc.y));
  acc.z = acc.z / (1.f + expf(-acc.z));
  acc.w = acc.w / (1.f + expf(-acc.w));
  *(float4*)(xc + (long)row * CONVD + c4) = acc;
}

// ================= chunked SSD scan =================
__global__ __launch_bounds__(256) void ssd_chunk_kernel(
    const float* __restrict__ xc, const float* __restrict__ dts,
    const float* __restrict__ glog, float* __restrict__ yss,
    float* __restrict__ Sbuf, float* __restrict__ EGbuf,
    float* __restrict__ Lam) {
  const int c = blockIdx.x & 15;
  const int h = (blockIdx.x >> 4) & 31;
  const int b = blockIdx.x >> 9;
  const int bh = b * NH + h;
  const long crow = (long)b * L_ + c * 64;
  const int tid = threadIdx.x, lane = tid & 63, wave = tid >> 6;

  __shared__ u16 Cs[64][72], Bs[64][72], Xt[64][72], Btw[64][72], Ms[64][72];
  __shared__ float Gs[64], wjL[64], dtL[64];

  if (wave == 0) {
    float g = glog[(crow + lane) * NH + h];
    float dt = dts[(crow + lane) * NH + h];
    float G = g;
    #pragma unroll
    for (int off = 1; off < 64; off <<= 1) {
      float t = __shfl_up(G, off, 64);
      if (lane >= off) G += t;
    }
    float G63 = __shfl(G, 63, 64);
    Gs[lane] = G;
    wjL[lane] = expf(G63 - G) * dt;
    dtL[lane] = dt;
    EGbuf[(bh * 16 + c) * 64 + lane] = expf(G);
    if (lane == 63) Lam[bh * 16 + c] = expf(G63);
  }
  __syncthreads();
  for (int idx = tid; idx < 1024; idx += 256) {
    int r = idx >> 4, c4 = (idx & 15) << 2;
    const float* row = xc + (crow + r) * CONVD;
    float4 xv = *(const float4*)(row + h * HD + c4);
    Xt[c4 + 0][r] = f2bf(xv.x); Xt[c4 + 1][r] = f2bf(xv.y);
    Xt[c4 + 2][r] = f2bf(xv.z); Xt[c4 + 3][r] = f2bf(xv.w);
    float4 bv = *(const float4*)(row + DI + c4);
    *(ushort4*)&Bs[r][c4] = make_ushort4(f2bf(bv.x), f2bf(bv.y), f2bf(bv.z), f2bf(bv.w));
    float w = wjL[r];
    Btw[c4 + 0][r] = f2bf(bv.x * w); Btw[c4 + 1][r] = f2bf(bv.y * w);
    Btw[c4 + 2][r] = f2bf(bv.z * w); Btw[c4 + 3][r] = f2bf(bv.w * w);
    float4 cv = *(const float4*)(row + DI + DSTATE + c4);
    *(ushort4*)&Cs[r][c4] = make_ushort4(f2bf(cv.x), f2bf(cv.y), f2bf(cv.z), f2bf(cv.w));
  }
  __syncthreads();

  const int mrow = wave * 16 + (lane & 15);
  const int quad = lane >> 4;
  f32x4 accE[4];
  #pragma unroll
  for (int j = 0; j < 4; ++j) accE[j] = (f32x4){0.f, 0.f, 0.f, 0.f};
  #pragma unroll
  for (int ks = 0; ks < 2; ++ks) {
    int k0 = ks * 32 + quad * 8;
    bf16x8 a = *(const bf16x8*)&Cs[mrow][k0];
    #pragma unroll
    for (int j = 0; j < 4; ++j) {
      bf16x8 bfr = *(const bf16x8*)&Bs[j * 16 + (lane & 15)][k0];
      accE[j] = __builtin_amdgcn_mfma_f32_16x16x32_bf16(a, bfr, accE[j], 0, 0, 0);
    }
  }
  #pragma unroll
  for (int j = 0; j < 4; ++j) {
    int jc = j * 16 + (lane & 15);
    float Gj = Gs[jc], dtj = dtL[jc];
    #pragma unroll
    for (int r = 0; r < 4; ++r) {
      int ir = wave * 16 + quad * 4 + r;
      float v = (ir >= jc) ? accE[j][r] * expf(Gs[ir] - Gj) * dtj : 0.f;
      Ms[ir][jc] = f2bf(v);
    }
  }
  __syncthreads();
  f32x4 accY[4], accS[4];
  #pragma unroll
  for (int j = 0; j < 4; ++j) { accY[j] = (f32x4){0.f,0.f,0.f,0.f}; accS[j] = (f32x4){0.f,0.f,0.f,0.f}; }
  #pragma unroll
  for (int ks = 0; ks < 2; ++ks) {
    int k0 = ks * 32 + quad * 8;
    bf16x8 aM = *(const bf16x8*)&Ms[mrow][k0];
    bf16x8 aX = *(const bf16x8*)&Xt[mrow][k0];
    #pragma unroll
    for (int j = 0; j < 4; ++j) {
      bf16x8 bX = *(const bf16x8*)&Xt[j * 16 + (lane & 15)][k0];
      bf16x8 bB = *(const bf16x8*)&Btw[j * 16 + (lane & 15)][k0];
      accY[j] = __builtin_amdgcn_mfma_f32_16x16x32_bf16(aM, bX, accY[j], 0, 0, 0);
      accS[j] = __builtin_amdgcn_mfma_f32_16x16x32_bf16(aX, bB, accS[j], 0, 0, 0);
    }
  }
  float* Sc = Sbuf + (long)(bh * 16 + c) * 4096;
  #pragma unroll
  for (int j = 0; j < 4; ++j) {
    int col = j * 16 + (lane & 15);
    #pragma unroll
    for (int r = 0; r < 4; ++r) {
      int mr = wave * 16 + quad * 4 + r;
      yss[(crow + mr) * DI + h * HD + col] = accY[j][r];
      Sc[mr * 64 + col] = accS[j][r];
    }
  }
}

__global__ __launch_bounds__(256) void ssd_combine_kernel(
    float* __restrict__ Sbuf, const float* __restrict__ Lam) {
  const int bh = blockIdx.x;
  float* base = Sbuf + (long)bh * 16 * 4096 + threadIdx.x * 16;
  float H[16];
  #pragma unroll
  for (int k = 0; k < 16; ++k) H[k] = 0.f;
  for (int cc = 0; cc < 16; ++cc) {
    float lam = Lam[bh * 16 + cc];
    float* p = base + cc * 4096;
    float tmp[16];
    #pragma unroll
    for (int k = 0; k < 16; k += 4) {
      float4 v = *(const float4*)(p + k);
      tmp[k] = v.x; tmp[k + 1] = v.y; tmp[k + 2] = v.z; tmp[k + 3] = v.w;
    }
    #pragma unroll
    for (int k = 0; k < 16; k += 4)
      *(float4*)(p + k) = make_float4(H[k], H[k + 1], H[k + 2], H[k + 3]);
    #pragma unroll
    for (int k = 0; k < 16; ++k) H[k] = fmaf(lam, H[k], tmp[k]);
  }
}

__global__ __launch_bounds__(256) void ssd_final_kernel(
    const float* __restrict__ xc, const float* __restrict__ Sbuf,
    const float* __restrict__ EGbuf, const float* __restrict__ Dp,
    float* __restrict__ yss) {
  const int c = blockIdx.x & 15;
  const int h = (blockIdx.x >> 4) & 31;
  const int b = blockIdx.x >> 9;
  const int bh = b * NH + h;
  const long crow = (long)b * L_ + c * 64;
  const int tid = threadIdx.x, lane = tid & 63, wave = tid >> 6;
  __shared__ u16 Csc[64][72], Hs[64][72];
  __shared__ float egL[64];
  if (tid < 64) egL[tid] = EGbuf[(bh * 16 + c) * 64 + tid];
  __syncthreads();
  const float* Sc = Sbuf + (long)(bh * 16 + c) * 4096;
  for (int idx = tid; idx < 1024; idx += 256) {
    int r = idx >> 4, c4 = (idx & 15) << 2;
    float4 hv = *(const float4*)(Sc + r * 64 + c4);
    *(ushort4*)&Hs[r][c4] = make_ushort4(f2bf(hv.x), f2bf(hv.y), f2bf(hv.z), f2bf(hv.w));
    float eg = egL[r];
    float4 cv = *(const float4*)(xc + (crow + r) * CONVD + DI + DSTATE + c4);
    *(ushort4*)&Csc[r][c4] = make_ushort4(f2bf(cv.x * eg), f2bf(cv.y * eg),
                                          f2bf(cv.z * eg), f2bf(cv.w * eg));
  }
  __syncthreads();
  const int mrow = wave * 16 + (lane & 15);
  const int quad = lane >> 4;
  f32x4 acc[4];
  #pragma unroll
  for (int j = 0; j < 4; ++j) acc[j] = (f32x4){0.f, 0.f, 0.f, 0.f};
  #pragma unroll
  for (int ks = 0; ks < 2; ++ks) {
    int k0 = ks * 32 + quad * 8;
    bf16x8 a = *(const bf16x8*)&Csc[mrow][k0];
    #pragma unroll
    for (int j = 0; j < 4; ++j) {
      bf16x8 bfr = *(const bf16x8*)&Hs[j * 16 + (lane & 15)][k0];
      acc[j] = __builtin_amdgcn_mfma_f32_16x16x32_bf16(a, bfr, acc[j], 0, 0, 0);
    }
  }
  const float Dh = Dp[h];
  #pragma unroll
  for (int j = 0; j < 4; ++j) {
    int p = j * 16 + (lane & 15);
    #pragma unroll
    for (int r = 0; r < 4; ++r) {
      int ir = wave * 16 + quad * 4 + r;
      long o = (crow + ir) * DI + h * HD + p;
      float xval = xc[(crow + ir) * CONVD + h * HD + p];
      yss[o] = yss[o] + acc[j][r] + Dh * xval;
    }
  }
}

// ---------------- gated rmsnorm ----------------
__global__ __launch_bounds__(256) void gated_rms_kernel(
    const float* __restrict__ y, const float* __restrict__ zx,
    const float* __restrict__ wt, u16* __restrict__ out) {
  const int row = blockIdx.x;
  const int c = threadIdx.x << 3;
  const float* yr = y + (long)row * DI + c;
  const float* zr = zx + (long)row * ZXS + c;
  float v[8];
  float ss = 0.f;
  #pragma unroll
  for (int i = 0; i < 8; i += 4) {
    float4 y4 = *(const float4*)(yr + i);
    float4 z4 = *(const float4*)(zr + i);
    const float zz[4] = {z4.x, z4.y, z4.z, z4.w};
    const float yy[4] = {y4.x, y4.y, y4.z, y4.w};
    #pragma unroll
    for (int j = 0; j < 4; ++j) {
      float sg = zz[j] / (1.f + expf(-zz[j]));
      float val = yy[j] * sg;
      v[i + j] = val;
      ss += val * val;
    }
  }
  float tot = block_reduce_sum256(ss);
  float sc = rsqrtf(tot * (1.0f / DI) + 1e-5f);
  const float* wr = wt + c;
  *(ushort4*)(out + (long)row * DI + c) =
      make_ushort4(f2bf(v[0] * sc * wr[0]), f2bf(v[1] * sc * wr[1]),
                   f2bf(v[2] * sc * wr[2]), f2bf(v[3] * sc * wr[3]));
  *(ushort4*)(out + (long)row * DI + c + 4) =
      make_ushort4(f2bf(v[4] * sc * wr[4]), f2bf(v[5] * sc * wr[5]),
                   f2bf(v[6] * sc * wr[6]), f2bf(v[7] * sc * wr[7]));
}

// ---------------- final elementwise ----------------
// ghb: [2048][2048] with g = cols 0..1023, h = cols 1024..2047
__global__ __launch_bounds__(256) void final_kernel(
    const float* __restrict__ xa, const float* __restrict__ ghb,
    const float* __restrict__ xd, const float* __restrict__ xf,
    float* __restrict__ out) {
  int i = blockIdx.x * 256 + threadIdx.x;   // float4 index over 2048*1024/4
  int row = i >> 8, col4 = i & 255;
  float4 g4 = ((const float4*)ghb)[row * 512 + col4];
  float4 h4 = ((const float4*)ghb)[row * 512 + 256 + col4];
  float4 a4 = ((const float4*)xa)[i];
  float4 d4 = ((const float4*)xd)[i];
  float4 f4 = ((const float4*)xf)[i];
  float4 o0, o1;
  float sg;
  sg = g4.x / (1.f + expf(-g4.x)); float e0 = sg * h4.x;
  sg = g4.y / (1.f + expf(-g4.y)); float e1 = sg * h4.y;
  sg = g4.z / (1.f + expf(-g4.z)); float e2 = sg * h4.z;
  sg = g4.w / (1.f + expf(-g4.w)); float e3 = sg * h4.w;
  o0.x = a4.x + e0; o0.y = a4.y + e1; o0.z = a4.z + e2; o0.w = a4.w + e3;
  o1.x = d4.x + f4.x + e0; o1.y = d4.y + f4.y + e1;
  o1.z = d4.z + f4.z + e2; o1.w = d4.w + f4.w + e3;
  ((float4*)out)[i] = o0;
  ((float4*)(out + (long)B_ * L_ * DM))[i] = o1;
}

extern "C" void kernel_launch(void* const* d_in, const int* in_sizes, int n_in,
                              void* d_out, int out_size, void* d_ws, size_t ws_size,
                              hipStream_t stream) {
  const float* x        = (const float*)d_in[0];
  const float* x_d      = (const float*)d_in[1];
  const float* norm_w   = (const float*)d_in[2];
  const float* W_in     = (const float*)d_in[3];
  const float* conv_w   = (const float*)d_in[4];
  const float* conv_b   = (const float*)d_in[5];
  const float* dt_bias  = (const float*)d_in[6];
  const float* A_log    = (const float*)d_in[7];
  const float* D_param  = (const float*)d_in[8];
  const float* ssm_w    = (const float*)d_in[9];
  const float* W_out    = (const float*)d_in[10];
  const float* w1       = (const float*)d_in[11];
  const float* w2       = (const float*)d_in[12];
  float* out = (float*)d_out;

  char* wsc = (char*)d_ws;
  size_t off = 0;
  auto alloc = [&](size_t n) { char* p = wsc + off; off += (n + 255) & ~(size_t)255; return p; };
  float* zx   = (float*)alloc((size_t)2048 * ZXS * 4);
  float* xc   = (float*)alloc((size_t)2048 * 2176 * 4);
  float* yss  = (float*)alloc((size_t)2048 * 2048 * 4);
  float* xf   = (float*)alloc((size_t)2048 * 1024 * 4);
  float* xa   = (float*)alloc((size_t)2048 * 1024 * 4);
  float* ghb  = (float*)alloc((size_t)2048 * 2048 * 4);
  float* dts  = (float*)alloc((size_t)65536 * 4);
  float* glog = (float*)alloc((size_t)65536 * 4);
  float* EGbuf= (float*)alloc((size_t)65536 * 4);
  float* Lam  = (float*)alloc((size_t)1024 * 4);
  u16* xlnb   = (u16*)alloc((size_t)2048 * 1024 * 2);
  u16* ygnb   = (u16*)alloc((size_t)2048 * 2048 * 2);
  u16* xln2b  = (u16*)alloc((size_t)2048 * 1024 * 2);
  u16* Winb   = (u16*)alloc((size_t)4256 * 1024 * 2);
  u16* Woutb  = (u16*)alloc((size_t)1024 * 2048 * 2);
  u16* w12b   = (u16*)alloc((size_t)2048 * 1024 * 2);
  // Sbuf (16.8 MB) aliases ghb: scan trio finishes before MLP GEMM writes ghb
  float* Sbuf = ghb;

  f32_to_bf16<<<(4256 * 1024 / 4 + 255) / 256, 256, 0, stream>>>(W_in, Winb, 4256 * 1024 / 4);
  f32_to_bf16<<<(1024 * 2048 / 4 + 255) / 256, 256, 0, stream>>>(W_out, Woutb, 1024 * 2048 / 4);
  f32_to_bf16<<<(1024 * 1024 / 4 + 255) / 256, 256, 0, stream>>>(w1, w12b, 1024 * 1024 / 4);
  f32_to_bf16<<<(1024 * 1024 / 4 + 255) / 256, 256, 0, stream>>>(w2, w12b + (size_t)1024 * 1024, 1024 * 1024 / 4);

  // 1) rmsnorm(x) -> bf16
  add_rms_kernel<<<2048, 256, 0, stream>>>(x, nullptr, nullptr, norm_w, xlnb, 1e-6f);
  // 2) in-proj: N stride 4352 (padded), valid B rows 4256
  gemm_lds<4><<<dim3(34, 16), 256, 0, stream>>>(xlnb, Winb, zx, ZXS, 4256, 1024);
  // 3) dt/dA and conv+silu
  dtA_kernel<<<256, 256, 0, stream>>>(zx, dt_bias, A_log, dts, glog);
  conv_silu_kernel<<<(2048 * 544 + 255) / 256, 256, 0, stream>>>(zx, conv_w, conv_b, xc);
  // 4) chunked SSD scan
  ssd_chunk_kernel<<<1024, 256, 0, stream>>>(xc, dts, glog, yss, Sbuf, EGbuf, Lam);
  ssd_combine_kernel<<<64, 256, 0, stream>>>(Sbuf, Lam);
  ssd_final_kernel<<<1024, 256, 0, stream>>>(xc, Sbuf, EGbuf, D_param, yss);
  // 5) gated rmsnorm -> bf16
  gated_rms_kernel<<<2048, 256, 0, stream>>>(yss, zx, ssm_w, ygnb);
  // 6) out-proj (128x64 tiles -> 256 blocks)
  gemm_lds<2><<<dim3(16, 16), 256, 0, stream>>>(ygnb, Woutb, xf, 1024, 1024, 2048);
  // 7) x_a = x + x_f; rmsnorm -> bf16
  add_rms_kernel<<<2048, 256, 0, stream>>>(x, xf, xa, norm_w, xln2b, 1e-6f);
  // 8) fused MLP GEMM (w1 || w2)
  gemm_lds<4><<<dim3(16, 16), 256, 0, stream>>>(xln2b, w12b, ghb, 2048, 2048, 1024);
  // 9) outputs
  final_kernel<<<2048, 256, 0, stream>>>(xa, ghb, x_d, xf, out);
}

// Round 4
// 288.266 us; speedup vs baseline: 2.9814x; 1.0588x over previous
//
#include <hip/hip_runtime.h>

typedef unsigned short u16;
typedef __attribute__((ext_vector_type(8))) short bf16x8;
typedef __attribute__((ext_vector_type(4))) float f32x4;

#define B_      2
#define L_      1024
#define DM      1024
#define DI      2048
#define NH      32
#define HD      64
#define DSTATE  64
#define CONVD   2176
#define DPROJ   4256
#define ZXS     4352   // padded zx row stride (34*128)

__device__ __forceinline__ u16 f2bf(float f) {
  union { float f; unsigned u; } v; v.f = f;
  unsigned r = v.u + 0x7fffu + ((v.u >> 16) & 1u);   // RNE
  return (u16)(r >> 16);
}

__device__ __forceinline__ void load_lds16(const void* g, void* l) {
  __builtin_amdgcn_global_load_lds(
      (const __attribute__((address_space(1))) void*)g,
      (__attribute__((address_space(3))) void*)l, 16, 0, 0);
}

__device__ __forceinline__ float block_reduce_sum256(float v) {
  #pragma unroll
  for (int off = 32; off > 0; off >>= 1) v += __shfl_down(v, off, 64);
  __shared__ float red[4];
  int lane = threadIdx.x & 63, w = threadIdx.x >> 6;
  if (lane == 0) red[w] = v;
  __syncthreads();
  return red[0] + red[1] + red[2] + red[3];
}

// ---------------- merged weight conversion ----------------
// Winb: 4256x1024, Woutb: 1024x2048, w12b: 2048x1024 ROW-INTERLEAVED (even=w1, odd=w2)
__global__ __launch_bounds__(256) void convert_weights(
    const float* __restrict__ W_in, const float* __restrict__ W_out,
    const float* __restrict__ w1, const float* __restrict__ w2,
    u16* __restrict__ Winb, u16* __restrict__ Woutb, u16* __restrict__ w12b) {
  const long R0 = 4256L * 1024 / 4;
  const long R1 = R0 + 2048L * 1024 / 4;
  long i = (long)blockIdx.x * 256 + threadIdx.x;
  float4 v;
  ushort4* dst;
  if (i < R0) {
    v = ((const float4*)W_in)[i];
    dst = ((ushort4*)Winb) + i;
  } else if (i < R1) {
    long j = i - R0;
    v = ((const float4*)W_out)[j];
    dst = ((ushort4*)Woutb) + j;
  } else {
    long j = i - R1;                 // float4 idx over 2048x1024 interleaved
    long row = j >> 8;
    long col = j & 255;
    const float* s = (row & 1) ? w2 : w1;
    v = ((const float4*)s)[(row >> 1) * 256 + col];
    dst = ((ushort4*)w12b) + j;
  }
  *dst = make_ushort4(f2bf(v.x), f2bf(v.y), f2bf(v.z), f2bf(v.w));
}

// ---------------- rmsnorm (optionally fused residual add) ----------------
__global__ __launch_bounds__(256) void add_rms_kernel(
    const float* __restrict__ in1, const float* __restrict__ in2,
    float* __restrict__ sum_out, const float* __restrict__ wt,
    u16* __restrict__ out, float eps) {
  const int row = blockIdx.x;
  const int c = threadIdx.x << 2;
  float4 v = *(const float4*)(in1 + (long)row * DM + c);
  if (in2) {
    float4 u = *(const float4*)(in2 + (long)row * DM + c);
    v.x += u.x; v.y += u.y; v.z += u.z; v.w += u.w;
  }
  if (sum_out) *(float4*)(sum_out + (long)row * DM + c) = v;
  float ss = v.x * v.x + v.y * v.y + v.z * v.z + v.w * v.w;
  float tot = block_reduce_sum256(ss);
  float sc = rsqrtf(tot * (1.0f / DM) + eps);
  float4 wv = *(const float4*)(wt + c);
  *(ushort4*)(out + (long)row * DM + c) =
      make_ushort4(f2bf(v.x * sc * wv.x), f2bf(v.y * sc * wv.y),
                   f2bf(v.z * sc * wv.z), f2bf(v.w * sc * wv.w));
}

// ============ bf16 NT GEMM: double-buffered LDS + fine-grained vmcnt ============
// C[m,n] = sum_k A[m,k]*Bw[n,k]. Tile 128 x (NJ*32), BK=64, 256 threads.
// XOR-swizzled LDS chunks; prefetch next K-tile before waiting on current.
template<int NJ>
__global__ __launch_bounds__(256) void gemm_lds(
    const u16* __restrict__ A, const u16* __restrict__ Bw,
    float* __restrict__ C, int N, int Nw, int K) {
  constexpr int BN = NJ * 32;
  __shared__ u16 As[2][128][64];
  __shared__ u16 Bs[2][BN][64];
  const int tid = threadIdx.x;
  const int lane = tid & 63;
  const int wave = tid >> 6;
  const int ml = lane & 15;
  const int quad = lane >> 4;
  const int wm = (wave & 1) << 6;
  const int wn = (wave >> 1) * (BN / 2);
  const long bm = (long)blockIdx.y << 7;
  const long bn = (long)blockIdx.x * BN;

  const int lr = lane >> 3;
  const int lc = (lane & 7) ^ lr;

  f32x4 acc[4][NJ];
  #pragma unroll
  for (int i = 0; i < 4; ++i)
    #pragma unroll
    for (int j = 0; j < NJ; ++j)
      acc[i][j] = (f32x4){0.f, 0.f, 0.f, 0.f};

  auto stage = [&](int kk, int buf) {
    #pragma unroll
    for (int t = 0; t < 4; ++t) {
      const int u = wave * 4 + t;
      const u16* g = A + (bm + u * 8 + lr) * K + kk + lc * 8;
      load_lds16(g, &As[buf][u * 8][0]);
    }
    #pragma unroll
    for (int t = 0; t < NJ; ++t) {
      const int u = wave * NJ + t;
      long brow = bn + u * 8 + lr;
      if (brow >= Nw) brow = Nw - 1;
      const u16* g = Bw + brow * K + kk + lc * 8;
      load_lds16(g, &Bs[buf][u * 8][0]);
    }
  };

  stage(0, 0);
  int buf = 0;
  for (int kt = 0; kt < K; kt += 64) {
    if (kt + 64 < K) {
      stage(kt + 64, buf ^ 1);
      // wait only for the OLDER (4+NJ) loads = current tile; keep prefetch in flight
      if constexpr (NJ == 4)
        asm volatile("s_waitcnt vmcnt(8)\n\ts_barrier" ::: "memory");
      else
        asm volatile("s_waitcnt vmcnt(6)\n\ts_barrier" ::: "memory");
    } else {
      asm volatile("s_waitcnt vmcnt(0)\n\ts_barrier" ::: "memory");
    }
    #pragma unroll
    for (int ks = 0; ks < 2; ++ks) {
      const int c = ks * 4 + quad;
      const int pc = (c ^ (ml & 7)) << 3;
      bf16x8 af[4], bfr[NJ];
      #pragma unroll
      for (int i = 0; i < 4; ++i)
        af[i] = *(const bf16x8*)&As[buf][wm + (i << 4) + ml][pc];
      #pragma unroll
      for (int j = 0; j < NJ; ++j)
        bfr[j] = *(const bf16x8*)&Bs[buf][wn + (j << 4) + ml][pc];
      #pragma unroll
      for (int i = 0; i < 4; ++i)
        #pragma unroll
        for (int j = 0; j < NJ; ++j)
          acc[i][j] = __builtin_amdgcn_mfma_f32_16x16x32_bf16(af[i], bfr[j], acc[i][j], 0, 0, 0);
    }
    asm volatile("s_barrier" ::: "memory");   // LDS WAR vs next iter's stage
    buf ^= 1;
  }

  const int rquad = quad << 2;
  #pragma unroll
  for (int i = 0; i < 4; ++i) {
    const long gm = bm + wm + (i << 4) + rquad;
    #pragma unroll
    for (int j = 0; j < NJ; ++j) {
      const long gn = bn + wn + (j << 4) + ml;
      #pragma unroll
      for (int r = 0; r < 4; ++r)
        C[(gm + r) * N + gn] = acc[i][j][r];
    }
  }
}

// ============ fused MLP GEMM + silu-gate + both outputs ============
// A = xln2b (2048x1024), Bw = w12b row-interleaved (2048x1024).
// col n even -> g (w1 row n/2), odd -> h (w2 row n/2). e = silu(g)*h.
// out0 = xa + e ; out1 = xd + xf + e. Direct store to d_out.
__global__ __launch_bounds__(256) void gemm_mlp_final(
    const u16* __restrict__ A, const u16* __restrict__ Bw,
    const float* __restrict__ xa, const float* __restrict__ xd,
    const float* __restrict__ xf, float* __restrict__ out, int K) {
  constexpr int NJ = 4;
  constexpr int BN = 128;
  __shared__ u16 As[2][128][64];
  __shared__ u16 Bs[2][BN][64];
  const int tid = threadIdx.x;
  const int lane = tid & 63;
  const int wave = tid >> 6;
  const int ml = lane & 15;
  const int quad = lane >> 4;
  const int wm = (wave & 1) << 6;
  const int wn = (wave >> 1) * 64;
  const long bm = (long)blockIdx.y << 7;
  const long bn = (long)blockIdx.x * BN;

  const int lr = lane >> 3;
  const int lc = (lane & 7) ^ lr;

  f32x4 acc[4][NJ];
  #pragma unroll
  for (int i = 0; i < 4; ++i)
    #pragma unroll
    for (int j = 0; j < NJ; ++j)
      acc[i][j] = (f32x4){0.f, 0.f, 0.f, 0.f};

  auto stage = [&](int kk, int buf) {
    #pragma unroll
    for (int t = 0; t < 4; ++t) {
      const int u = wave * 4 + t;
      load_lds16(A + (bm + u * 8 + lr) * K + kk + lc * 8, &As[buf][u * 8][0]);
    }
    #pragma unroll
    for (int t = 0; t < NJ; ++t) {
      const int u = wave * NJ + t;
      load_lds16(Bw + (bn + u * 8 + lr) * K + kk + lc * 8, &Bs[buf][u * 8][0]);
    }
  };

  stage(0, 0);
  int buf = 0;
  for (int kt = 0; kt < K; kt += 64) {
    if (kt + 64 < K) {
      stage(kt + 64, buf ^ 1);
      asm volatile("s_waitcnt vmcnt(8)\n\ts_barrier" ::: "memory");
    } else {
      asm volatile("s_waitcnt vmcnt(0)\n\ts_barrier" ::: "memory");
    }
    #pragma unroll
    for (int ks = 0; ks < 2; ++ks) {
      const int c = ks * 4 + quad;
      const int pc = (c ^ (ml & 7)) << 3;
      bf16x8 af[4], bfr[NJ];
      #pragma unroll
      for (int i = 0; i < 4; ++i)
        af[i] = *(const bf16x8*)&As[buf][wm + (i << 4) + ml][pc];
      #pragma unroll
      for (int j = 0; j < NJ; ++j)
        bfr[j] = *(const bf16x8*)&Bs[buf][wn + (j << 4) + ml][pc];
      #pragma unroll
      for (int i = 0; i < 4; ++i)
        #pragma unroll
        for (int j = 0; j < NJ; ++j)
          acc[i][j] = __builtin_amdgcn_mfma_f32_16x16x32_bf16(af[i], bfr[j], acc[i][j], 0, 0, 0);
    }
    asm volatile("s_barrier" ::: "memory");
    buf ^= 1;
  }

  float* out1 = out + (long)B_ * L_ * DM;
  const int rquad = quad << 2;
  #pragma unroll
  for (int i = 0; i < 4; ++i) {
    const long gm = bm + wm + (i << 4) + rquad;
    #pragma unroll
    for (int j = 0; j < NJ; ++j) {
      const long gn = bn + wn + (j << 4) + ml;   // parity = ml parity
      #pragma unroll
      for (int r = 0; r < 4; ++r) {
        float v = acc[i][j][r];
        float p = __shfl_xor(v, 1, 64);          // even lane receives h
        if ((ml & 1) == 0) {
          float e = (v / (1.f + expf(-v))) * p;  // silu(g)*h
          long row = gm + r;
          long col = gn >> 1;
          long o = row * DM + col;
          out[o]  = xa[o] + e;
          out1[o] = xd[o] + xf[o] + e;
        }
      }
    }
  }
}

// ---------------- depthwise causal conv (k=4) + silu ----------------
__global__ __launch_bounds__(256) void conv_silu_kernel(
    const float* __restrict__ zx, const float* __restrict__ cw,
    const float* __restrict__ cb, float* __restrict__ xc) {
  int idx = blockIdx.x * 256 + threadIdx.x;
  if (idx >= 2048 * 544) return;
  const int c4 = (idx % 544) << 2;
  const int row = idx / 544;
  const int t = row & (L_ - 1);
  float4 acc = *(const float4*)(cb + c4);
  float4 w0 = *(const float4*)(cw + (c4 + 0) * 4);
  float4 w1v = *(const float4*)(cw + (c4 + 1) * 4);
  float4 w2v = *(const float4*)(cw + (c4 + 2) * 4);
  float4 w3v = *(const float4*)(cw + (c4 + 3) * 4);
  const float wts[4][4] = {{w0.x, w0.y, w0.z, w0.w},
                           {w1v.x, w1v.y, w1v.z, w1v.w},
                           {w2v.x, w2v.y, w2v.z, w2v.w},
                           {w3v.x, w3v.y, w3v.z, w3v.w}};
  #pragma unroll
  for (int i = 0; i < 4; ++i) {
    int tau = t - 3 + i;
    if (tau >= 0) {
      float4 xv = *(const float4*)(zx + (long)(row - t + tau) * ZXS + DI + c4);
      acc.x = fmaf(xv.x, wts[0][i], acc.x);
      acc.y = fmaf(xv.y, wts[1][i], acc.y);
      acc.z = fmaf(xv.z, wts[2][i], acc.z);
      acc.w = fmaf(xv.w, wts[3][i], acc.w);
    }
  }
  acc.x = acc.x / (1.f + expf(-acc.x));
  acc.y = acc.y / (1.f + expf(-acc.y));
  acc.z = acc.z / (1.f + expf(-acc.z));
  acc.w = acc.w / (1.f + expf(-acc.w));
  *(float4*)(xc + (long)row * CONVD + c4) = acc;
}

// ================= chunked SSD scan (dt/softplus fused into wave0) =================
__global__ __launch_bounds__(256) void ssd_chunk_kernel(
    const float* __restrict__ xc, const float* __restrict__ zx,
    const float* __restrict__ dt_bias, const float* __restrict__ A_log,
    float* __restrict__ yss, float* __restrict__ Sbuf,
    float* __restrict__ EGbuf, float* __restrict__ Lam) {
  const int c = blockIdx.x & 15;
  const int h = (blockIdx.x >> 4) & 31;
  const int b = blockIdx.x >> 9;
  const int bh = b * NH + h;
  const long crow = (long)b * L_ + c * 64;
  const int tid = threadIdx.x, lane = tid & 63, wave = tid >> 6;

  __shared__ u16 Cs[64][72], Bs[64][72], Xt[64][72], Btw[64][72], Ms[64][72];
  __shared__ float Gs[64], wjL[64], dtL[64];

  if (wave == 0) {
    float draw = zx[(crow + lane) * ZXS + (DI + CONVD) + h] + dt_bias[h];
    float dt = (draw > 20.f) ? draw : log1pf(expf(draw));
    float g = -expf(A_log[h]) * dt;
    float G = g;
    #pragma unroll
    for (int off = 1; off < 64; off <<= 1) {
      float t = __shfl_up(G, off, 64);
      if (lane >= off) G += t;
    }
    float G63 = __shfl(G, 63, 64);
    Gs[lane] = G;
    wjL[lane] = expf(G63 - G) * dt;
    dtL[lane] = dt;
    EGbuf[(bh * 16 + c) * 64 + lane] = expf(G);
    if (lane == 63) Lam[bh * 16 + c] = expf(G63);
  }
  __syncthreads();
  for (int idx = tid; idx < 1024; idx += 256) {
    int r = idx >> 4, c4 = (idx & 15) << 2;
    const float* row = xc + (crow + r) * CONVD;
    float4 xv = *(const float4*)(row + h * HD + c4);
    Xt[c4 + 0][r] = f2bf(xv.x); Xt[c4 + 1][r] = f2bf(xv.y);
    Xt[c4 + 2][r] = f2bf(xv.z); Xt[c4 + 3][r] = f2bf(xv.w);
    float4 bv = *(const float4*)(row + DI + c4);
    *(ushort4*)&Bs[r][c4] = make_ushort4(f2bf(bv.x), f2bf(bv.y), f2bf(bv.z), f2bf(bv.w));
    float w = wjL[r];
    Btw[c4 + 0][r] = f2bf(bv.x * w); Btw[c4 + 1][r] = f2bf(bv.y * w);
    Btw[c4 + 2][r] = f2bf(bv.z * w); Btw[c4 + 3][r] = f2bf(bv.w * w);
    float4 cv = *(const float4*)(row + DI + DSTATE + c4);
    *(ushort4*)&Cs[r][c4] = make_ushort4(f2bf(cv.x), f2bf(cv.y), f2bf(cv.z), f2bf(cv.w));
  }
  __syncthreads();

  const int mrow = wave * 16 + (lane & 15);
  const int quad = lane >> 4;
  f32x4 accE[4];
  #pragma unroll
  for (int j = 0; j < 4; ++j) accE[j] = (f32x4){0.f, 0.f, 0.f, 0.f};
  #pragma unroll
  for (int ks = 0; ks < 2; ++ks) {
    int k0 = ks * 32 + quad * 8;
    bf16x8 a = *(const bf16x8*)&Cs[mrow][k0];
    #pragma unroll
    for (int j = 0; j < 4; ++j) {
      bf16x8 bfr = *(const bf16x8*)&Bs[j * 16 + (lane & 15)][k0];
      accE[j] = __builtin_amdgcn_mfma_f32_16x16x32_bf16(a, bfr, accE[j], 0, 0, 0);
    }
  }
  #pragma unroll
  for (int j = 0; j < 4; ++j) {
    int jc = j * 16 + (lane & 15);
    float Gj = Gs[jc], dtj = dtL[jc];
    #pragma unroll
    for (int r = 0; r < 4; ++r) {
      int ir = wave * 16 + quad * 4 + r;
      float v = (ir >= jc) ? accE[j][r] * expf(Gs[ir] - Gj) * dtj : 0.f;
      Ms[ir][jc] = f2bf(v);
    }
  }
  __syncthreads();
  f32x4 accY[4], accS[4];
  #pragma unroll
  for (int j = 0; j < 4; ++j) { accY[j] = (f32x4){0.f,0.f,0.f,0.f}; accS[j] = (f32x4){0.f,0.f,0.f,0.f}; }
  #pragma unroll
  for (int ks = 0; ks < 2; ++ks) {
    int k0 = ks * 32 + quad * 8;
    bf16x8 aM = *(const bf16x8*)&Ms[mrow][k0];
    bf16x8 aX = *(const bf16x8*)&Xt[mrow][k0];
    #pragma unroll
    for (int j = 0; j < 4; ++j) {
      bf16x8 bX = *(const bf16x8*)&Xt[j * 16 + (lane & 15)][k0];
      bf16x8 bB = *(const bf16x8*)&Btw[j * 16 + (lane & 15)][k0];
      accY[j] = __builtin_amdgcn_mfma_f32_16x16x32_bf16(aM, bX, accY[j], 0, 0, 0);
      accS[j] = __builtin_amdgcn_mfma_f32_16x16x32_bf16(aX, bB, accS[j], 0, 0, 0);
    }
  }
  float* Sc = Sbuf + (long)(bh * 16 + c) * 4096;
  #pragma unroll
  for (int j = 0; j < 4; ++j) {
    int col = j * 16 + (lane & 15);
    #pragma unroll
    for (int r = 0; r < 4; ++r) {
      int mr = wave * 16 + quad * 4 + r;
      yss[(crow + mr) * DI + h * HD + col] = accY[j][r];
      Sc[mr * 64 + col] = accS[j][r];
    }
  }
}

// S2: parallel serial-combine: one thread per state element, 16x more blocks
__global__ __launch_bounds__(256) void ssd_combine_kernel(
    float* __restrict__ Sbuf, const float* __restrict__ Lam) {
  const int bh = blockIdx.x >> 4;
  const int e = (blockIdx.x & 15) * 256 + threadIdx.x;   // 0..4095
  float* base = Sbuf + (long)bh * 16 * 4096 + e;
  const float* lamp = Lam + bh * 16;
  float H = 0.f;
  for (int cc = 0; cc < 16; ++cc) {
    float lam = lamp[cc];
    float v = base[cc * 4096];
    base[cc * 4096] = H;
    H = fmaf(lam, H, v);
  }
}

__global__ __launch_bounds__(256) void ssd_final_kernel(
    const float* __restrict__ xc, const float* __restrict__ Sbuf,
    const float* __restrict__ EGbuf, const float* __restrict__ Dp,
    float* __restrict__ yss) {
  const int c = blockIdx.x & 15;
  const int h = (blockIdx.x >> 4) & 31;
  const int b = blockIdx.x >> 9;
  const int bh = b * NH + h;
  const long crow = (long)b * L_ + c * 64;
  const int tid = threadIdx.x, lane = tid & 63, wave = tid >> 6;
  __shared__ u16 Csc[64][72], Hs[64][72];
  __shared__ float egL[64];
  if (tid < 64) egL[tid] = EGbuf[(bh * 16 + c) * 64 + tid];
  __syncthreads();
  const float* Sc = Sbuf + (long)(bh * 16 + c) * 4096;
  for (int idx = tid; idx < 1024; idx += 256) {
    int r = idx >> 4, c4 = (idx & 15) << 2;
    float4 hv = *(const float4*)(Sc + r * 64 + c4);
    *(ushort4*)&Hs[r][c4] = make_ushort4(f2bf(hv.x), f2bf(hv.y), f2bf(hv.z), f2bf(hv.w));
    float eg = egL[r];
    float4 cv = *(const float4*)(xc + (crow + r) * CONVD + DI + DSTATE + c4);
    *(ushort4*)&Csc[r][c4] = make_ushort4(f2bf(cv.x * eg), f2bf(cv.y * eg),
                                          f2bf(cv.z * eg), f2bf(cv.w * eg));
  }
  __syncthreads();
  const int mrow = wave * 16 + (lane & 15);
  const int quad = lane >> 4;
  f32x4 acc[4];
  #pragma unroll
  for (int j = 0; j < 4; ++j) acc[j] = (f32x4){0.f, 0.f, 0.f, 0.f};
  #pragma unroll
  for (int ks = 0; ks < 2; ++ks) {
    int k0 = ks * 32 + quad * 8;
    bf16x8 a = *(const bf16x8*)&Csc[mrow][k0];
    #pragma unroll
    for (int j = 0; j < 4; ++j) {
      bf16x8 bfr = *(const bf16x8*)&Hs[j * 16 + (lane & 15)][k0];
      acc[j] = __builtin_amdgcn_mfma_f32_16x16x32_bf16(a, bfr, acc[j], 0, 0, 0);
    }
  }
  const float Dh = Dp[h];
  #pragma unroll
  for (int j = 0; j < 4; ++j) {
    int p = j * 16 + (lane & 15);
    #pragma unroll
    for (int r = 0; r < 4; ++r) {
      int ir = wave * 16 + quad * 4 + r;
      long o = (crow + ir) * DI + h * HD + p;
      float xval = xc[(crow + ir) * CONVD + h * HD + p];
      yss[o] = yss[o] + acc[j][r] + Dh * xval;
    }
  }
}

// ---------------- gated rmsnorm ----------------
__global__ __launch_bounds__(256) void gated_rms_kernel(
    const float* __restrict__ y, const float* __restrict__ zx,
    const float* __restrict__ wt, u16* __restrict__ out) {
  const int row = blockIdx.x;
  const int c = threadIdx.x << 3;
  const float* yr = y + (long)row * DI + c;
  const float* zr = zx + (long)row * ZXS + c;
  float v[8];
  float ss = 0.f;
  #pragma unroll
  for (int i = 0; i < 8; i += 4) {
    float4 y4 = *(const float4*)(yr + i);
    float4 z4 = *(const float4*)(zr + i);
    const float zz[4] = {z4.x, z4.y, z4.z, z4.w};
    const float yy[4] = {y4.x, y4.y, y4.z, y4.w};
    #pragma unroll
    for (int j = 0; j < 4; ++j) {
      float sg = zz[j] / (1.f + expf(-zz[j]));
      float val = yy[j] * sg;
      v[i + j] = val;
      ss += val * val;
    }
  }
  float tot = block_reduce_sum256(ss);
  float sc = rsqrtf(tot * (1.0f / DI) + 1e-5f);
  const float* wr = wt + c;
  *(ushort4*)(out + (long)row * DI + c) =
      make_ushort4(f2bf(v[0] * sc * wr[0]), f2bf(v[1] * sc * wr[1]),
                   f2bf(v[2] * sc * wr[2]), f2bf(v[3] * sc * wr[3]));
  *(ushort4*)(out + (long)row * DI + c + 4) =
      make_ushort4(f2bf(v[4] * sc * wr[4]), f2bf(v[5] * sc * wr[5]),
                   f2bf(v[6] * sc * wr[6]), f2bf(v[7] * sc * wr[7]));
}

extern "C" void kernel_launch(void* const* d_in, const int* in_sizes, int n_in,
                              void* d_out, int out_size, void* d_ws, size_t ws_size,
                              hipStream_t stream) {
  const float* x        = (const float*)d_in[0];
  const float* x_d      = (const float*)d_in[1];
  const float* norm_w   = (const float*)d_in[2];
  const float* W_in     = (const float*)d_in[3];
  const float* conv_w   = (const float*)d_in[4];
  const float* conv_b   = (const float*)d_in[5];
  const float* dt_bias  = (const float*)d_in[6];
  const float* A_log    = (const float*)d_in[7];
  const float* D_param  = (const float*)d_in[8];
  const float* ssm_w    = (const float*)d_in[9];
  const float* W_out    = (const float*)d_in[10];
  const float* w1       = (const float*)d_in[11];
  const float* w2       = (const float*)d_in[12];
  float* out = (float*)d_out;

  char* wsc = (char*)d_ws;
  size_t off = 0;
  auto alloc = [&](size_t n) { char* p = wsc + off; off += (n + 255) & ~(size_t)255; return p; };
  float* zx   = (float*)alloc((size_t)2048 * ZXS * 4);
  float* xc   = (float*)alloc((size_t)2048 * 2176 * 4);
  float* yss  = (float*)alloc((size_t)2048 * 2048 * 4);
  float* xf   = (float*)alloc((size_t)2048 * 1024 * 4);
  float* xa   = (float*)alloc((size_t)2048 * 1024 * 4);
  float* Sbuf = (float*)alloc((size_t)1024 * 16 * 4096 / 16 * 4);  // 64 bh * 16 c * 4096 f32
  float* EGbuf= (float*)alloc((size_t)65536 * 4);
  float* Lam  = (float*)alloc((size_t)1024 * 4);
  u16* xlnb   = (u16*)alloc((size_t)2048 * 1024 * 2);
  u16* ygnb   = (u16*)alloc((size_t)2048 * 2048 * 2);
  u16* xln2b  = (u16*)alloc((size_t)2048 * 1024 * 2);
  u16* Winb   = (u16*)alloc((size_t)4256 * 1024 * 2);
  u16* Woutb  = (u16*)alloc((size_t)1024 * 2048 * 2);
  u16* w12b   = (u16*)alloc((size_t)2048 * 1024 * 2);

  // 0) all weight conversions in one launch (w12b row-interleaved w1/w2)
  convert_weights<<<8352, 256, 0, stream>>>(W_in, W_out, w1, w2, Winb, Woutb, w12b);
  // 1) rmsnorm(x) -> bf16
  add_rms_kernel<<<2048, 256, 0, stream>>>(x, nullptr, nullptr, norm_w, xlnb, 1e-6f);
  // 2) in-proj: N stride 4352 (padded), valid B rows 4256
  gemm_lds<4><<<dim3(34, 16), 256, 0, stream>>>(xlnb, Winb, zx, ZXS, 4256, 1024);
  // 3) conv+silu
  conv_silu_kernel<<<(2048 * 544 + 255) / 256, 256, 0, stream>>>(zx, conv_w, conv_b, xc);
  // 4) chunked SSD scan (dt/dA fused into chunk kernel)
  ssd_chunk_kernel<<<1024, 256, 0, stream>>>(xc, zx, dt_bias, A_log, yss, Sbuf, EGbuf, Lam);
  ssd_combine_kernel<<<1024, 256, 0, stream>>>(Sbuf, Lam);
  ssd_final_kernel<<<1024, 256, 0, stream>>>(xc, Sbuf, EGbuf, D_param, yss);
  // 5) gated rmsnorm -> bf16
  gated_rms_kernel<<<2048, 256, 0, stream>>>(yss, zx, ssm_w, ygnb);
  // 6) out-proj (128x64 tiles -> 256 blocks)
  gemm_lds<2><<<dim3(16, 16), 256, 0, stream>>>(ygnb, Woutb, xf, 1024, 1024, 2048);
  // 7) x_a = x + x_f; rmsnorm -> bf16
  add_rms_kernel<<<2048, 256, 0, stream>>>(x, xf, xa, norm_w, xln2b, 1e-6f);
  // 8) fused MLP GEMM + gate + final outputs (writes d_out directly)
  gemm_mlp_final<<<dim3(16, 16), 256, 0, stream>>>(xln2b, w12b, xa, x_d, xf, out, 1024);
}

// Round 5
// 261.487 us; speedup vs baseline: 3.2868x; 1.1024x over previous
//
#include <hip/hip_runtime.h>

typedef unsigned short u16;
typedef __attribute__((ext_vector_type(8))) short bf16x8;
typedef __attribute__((ext_vector_type(4))) float f32x4;

#define B_      2
#define L_      1024
#define DM      1024
#define DI      2048
#define NH      32
#define HD      64
#define DSTATE  64
#define CONVD   2176
#define DPROJ   4256
#define ZXS     4352   // padded zx row stride (34*128)

__device__ __forceinline__ u16 f2bf(float f) {
  union { float f; unsigned u; } v; v.f = f;
  unsigned r = v.u + 0x7fffu + ((v.u >> 16) & 1u);   // RNE
  return (u16)(r >> 16);
}

__device__ __forceinline__ void load_lds16(const void* g, void* l) {
  __builtin_amdgcn_global_load_lds(
      (const __attribute__((address_space(1))) void*)g,
      (__attribute__((address_space(3))) void*)l, 16, 0, 0);
}

template<int P> __device__ __forceinline__ void wait_prefetch() {
  if constexpr (P == 4)      asm volatile("s_waitcnt vmcnt(4)\n\ts_barrier" ::: "memory");
  else if constexpr (P == 6) asm volatile("s_waitcnt vmcnt(6)\n\ts_barrier" ::: "memory");
  else if constexpr (P == 8) asm volatile("s_waitcnt vmcnt(8)\n\ts_barrier" ::: "memory");
}

__device__ __forceinline__ float block_reduce_sum256(float v) {
  #pragma unroll
  for (int off = 32; off > 0; off >>= 1) v += __shfl_down(v, off, 64);
  __shared__ float red[4];
  int lane = threadIdx.x & 63, w = threadIdx.x >> 6;
  if (lane == 0) red[w] = v;
  __syncthreads();
  return red[0] + red[1] + red[2] + red[3];
}

// ---------------- merged weight conversion ----------------
// Winb: 4256x1024, Woutb: 1024x2048, w12b: [w1 (1024x1024); w2 (1024x1024)]
__global__ __launch_bounds__(256) void convert_weights(
    const float* __restrict__ W_in, const float* __restrict__ W_out,
    const float* __restrict__ w1, const float* __restrict__ w2,
    u16* __restrict__ Winb, u16* __restrict__ Woutb, u16* __restrict__ w12b) {
  const long R0 = 4256L * 1024 / 4;
  const long R1 = R0 + 2048L * 1024 / 4;
  long i = (long)blockIdx.x * 256 + threadIdx.x;
  float4 v;
  ushort4* dst;
  if (i < R0) {
    v = ((const float4*)W_in)[i];
    dst = ((ushort4*)Winb) + i;
  } else if (i < R1) {
    long j = i - R0;
    v = ((const float4*)W_out)[j];
    dst = ((ushort4*)Woutb) + j;
  } else {
    long j = i - R1;                 // float4 idx over 2048x1024 concat
    long row = j >> 8;
    const float* s = (row < 1024) ? (w1 + row * 1024) : (w2 + (row - 1024) * 1024);
    v = ((const float4*)s)[j & 255];
    dst = ((ushort4*)w12b) + j;
  }
  *dst = make_ushort4(f2bf(v.x), f2bf(v.y), f2bf(v.z), f2bf(v.w));
}

// ---------------- rmsnorm (optionally fused residual add) ----------------
__global__ __launch_bounds__(256) void add_rms_kernel(
    const float* __restrict__ in1, const float* __restrict__ in2,
    float* __restrict__ sum_out, const float* __restrict__ wt,
    u16* __restrict__ out, float eps) {
  const int row = blockIdx.x;
  const int c = threadIdx.x << 2;
  float4 v = *(const float4*)(in1 + (long)row * DM + c);
  if (in2) {
    float4 u = *(const float4*)(in2 + (long)row * DM + c);
    v.x += u.x; v.y += u.y; v.z += u.z; v.w += u.w;
  }
  if (sum_out) *(float4*)(sum_out + (long)row * DM + c) = v;
  float ss = v.x * v.x + v.y * v.y + v.z * v.z + v.w * v.w;
  float tot = block_reduce_sum256(ss);
  float sc = rsqrtf(tot * (1.0f / DM) + eps);
  float4 wv = *(const float4*)(wt + c);
  *(ushort4*)(out + (long)row * DM + c) =
      make_ushort4(f2bf(v.x * sc * wv.x), f2bf(v.y * sc * wv.y),
                   f2bf(v.z * sc * wv.z), f2bf(v.w * sc * wv.w));
}

// ============ bf16 NT GEMM: tile (NI*32) x (NJ*32), dbuf LDS + vmcnt prefetch ============
// C[m,n] = sum_k A[m,k]*Bw[n,k]. 256 threads, waves 2x2 over (M,N).
template<int NI, int NJ>
__global__ __launch_bounds__(256) void gemm_lds(
    const u16* __restrict__ A, const u16* __restrict__ Bw,
    float* __restrict__ C, int N, int Nw, int K) {
  constexpr int BM = NI * 32;
  constexpr int BN = NJ * 32;
  __shared__ u16 As[2][BM][64];
  __shared__ u16 Bs[2][BN][64];
  const int tid = threadIdx.x;
  const int lane = tid & 63;
  const int wave = tid >> 6;
  const int ml = lane & 15;
  const int quad = lane >> 4;
  const int wm = (wave & 1) * (NI * 16);
  const int wn = (wave >> 1) * (NJ * 16);
  const long bm = (long)blockIdx.y * BM;
  const long bn = (long)blockIdx.x * BN;

  const int lr = lane >> 3;
  const int lc = (lane & 7) ^ lr;

  f32x4 acc[NI][NJ];
  #pragma unroll
  for (int i = 0; i < NI; ++i)
    #pragma unroll
    for (int j = 0; j < NJ; ++j)
      acc[i][j] = (f32x4){0.f, 0.f, 0.f, 0.f};

  auto stage = [&](int kk, int buf) {
    #pragma unroll
    for (int t = 0; t < BM / 32; ++t) {
      const int u = wave * (BM / 32) + t;
      load_lds16(A + (bm + u * 8 + lr) * K + kk + lc * 8, &As[buf][u * 8][0]);
    }
    #pragma unroll
    for (int t = 0; t < BN / 32; ++t) {
      const int u = wave * (BN / 32) + t;
      long brow = bn + u * 8 + lr;
      if (brow >= Nw) brow = Nw - 1;
      load_lds16(Bw + brow * K + kk + lc * 8, &Bs[buf][u * 8][0]);
    }
  };

  stage(0, 0);
  int buf = 0;
  for (int kt = 0; kt < K; kt += 64) {
    if (kt + 64 < K) {
      stage(kt + 64, buf ^ 1);
      wait_prefetch<NI + NJ>();
    } else {
      asm volatile("s_waitcnt vmcnt(0)\n\ts_barrier" ::: "memory");
    }
    #pragma unroll
    for (int ks = 0; ks < 2; ++ks) {
      const int c = ks * 4 + quad;
      const int pc = (c ^ (ml & 7)) << 3;
      bf16x8 af[NI], bfr[NJ];
      #pragma unroll
      for (int i = 0; i < NI; ++i)
        af[i] = *(const bf16x8*)&As[buf][wm + (i << 4) + ml][pc];
      #pragma unroll
      for (int j = 0; j < NJ; ++j)
        bfr[j] = *(const bf16x8*)&Bs[buf][wn + (j << 4) + ml][pc];
      #pragma unroll
      for (int i = 0; i < NI; ++i)
        #pragma unroll
        for (int j = 0; j < NJ; ++j)
          acc[i][j] = __builtin_amdgcn_mfma_f32_16x16x32_bf16(af[i], bfr[j], acc[i][j], 0, 0, 0);
    }
    asm volatile("s_barrier" ::: "memory");   // LDS WAR vs next iter's stage
    buf ^= 1;
  }

  const int rquad = quad << 2;
  #pragma unroll
  for (int i = 0; i < NI; ++i) {
    const long gm = bm + wm + (i << 4) + rquad;
    #pragma unroll
    for (int j = 0; j < NJ; ++j) {
      const long gn = bn + wn + (j << 4) + ml;
      #pragma unroll
      for (int r = 0; r < 4; ++r)
        C[(gm + r) * N + gn] = acc[i][j][r];
    }
  }
}

// ============ fused MLP GEMM + silu-gate + both outputs (g/h split tile) ============
// A = xln2b (2048x1024). w12b = [w1;w2] concat. Block: 64 M-rows x 64 out-cols.
// B-tile: 128 rows = w1[c0..c0+64) stacked over w2[c0..c0+64).
// Wave: 32 M-rows x 32 cols; j=0,1 -> g frags, j=2,3 -> h frags (same cols).
__global__ __launch_bounds__(256) void gemm_mlp_final(
    const u16* __restrict__ A, const u16* __restrict__ Bw,
    const float* __restrict__ xa, const float* __restrict__ xd,
    const float* __restrict__ xf, float* __restrict__ out, int K) {
  __shared__ u16 As[2][64][64];
  __shared__ u16 Bs[2][128][64];
  const int tid = threadIdx.x;
  const int lane = tid & 63;
  const int wave = tid >> 6;
  const int ml = lane & 15;
  const int quad = lane >> 4;
  const int wm = (wave & 1) * 32;
  const int wn = (wave >> 1) * 32;          // col offset within block's 64 cols
  const long bm = (long)blockIdx.y * 64;
  const long c0 = (long)blockIdx.x * 64;    // output column base

  const int lr = lane >> 3;
  const int lc = (lane & 7) ^ lr;

  f32x4 acc[2][4];
  #pragma unroll
  for (int i = 0; i < 2; ++i)
    #pragma unroll
    for (int j = 0; j < 4; ++j)
      acc[i][j] = (f32x4){0.f, 0.f, 0.f, 0.f};

  auto stage = [&](int kk, int buf) {
    #pragma unroll
    for (int t = 0; t < 2; ++t) {
      const int u = wave * 2 + t;           // 0..7 -> 64 A rows
      load_lds16(A + (bm + u * 8 + lr) * K + kk + lc * 8, &As[buf][u * 8][0]);
    }
    #pragma unroll
    for (int t = 0; t < 4; ++t) {
      const int u = wave * 4 + t;           // 0..15 -> 128 B rows
      const int r = u * 8 + lr;             // LDS row
      const long grow = (r < 64) ? (c0 + r) : (1024 + c0 + (r - 64));
      load_lds16(Bw + grow * K + kk + lc * 8, &Bs[buf][u * 8][0]);
    }
  };

  stage(0, 0);
  int buf = 0;
  for (int kt = 0; kt < K; kt += 64) {
    if (kt + 64 < K) {
      stage(kt + 64, buf ^ 1);
      wait_prefetch<6>();
    } else {
      asm volatile("s_waitcnt vmcnt(0)\n\ts_barrier" ::: "memory");
    }
    #pragma unroll
    for (int ks = 0; ks < 2; ++ks) {
      const int c = ks * 4 + quad;
      const int pc = (c ^ (ml & 7)) << 3;
      bf16x8 af[2], bfr[4];
      #pragma unroll
      for (int i = 0; i < 2; ++i)
        af[i] = *(const bf16x8*)&As[buf][wm + (i << 4) + ml][pc];
      #pragma unroll
      for (int j = 0; j < 2; ++j) {
        bfr[j]     = *(const bf16x8*)&Bs[buf][wn + (j << 4) + ml][pc];        // w1 (g)
        bfr[j + 2] = *(const bf16x8*)&Bs[buf][64 + wn + (j << 4) + ml][pc];   // w2 (h)
      }
      #pragma unroll
      for (int i = 0; i < 2; ++i)
        #pragma unroll
        for (int j = 0; j < 4; ++j)
          acc[i][j] = __builtin_amdgcn_mfma_f32_16x16x32_bf16(af[i], bfr[j], acc[i][j], 0, 0, 0);
    }
    asm volatile("s_barrier" ::: "memory");
    buf ^= 1;
  }

  float* out1 = out + (long)B_ * L_ * DM;
  const int rquad = quad << 2;
  #pragma unroll
  for (int i = 0; i < 2; ++i) {
    const long gm = bm + wm + (i << 4) + rquad;
    #pragma unroll
    for (int jj = 0; jj < 2; ++jj) {
      const long col = c0 + wn + (jj << 4) + ml;
      #pragma unroll
      for (int r = 0; r < 4; ++r) {
        float g = acc[i][jj][r];
        float h = acc[i][jj + 2][r];
        float e = (g / (1.f + expf(-g))) * h;   // silu(g)*h
        long o = (gm + r) * DM + col;
        out[o]  = xa[o] + e;
        out1[o] = xd[o] + xf[o] + e;
      }
    }
  }
}

// ---------------- depthwise causal conv (k=4) + silu ----------------
__global__ __launch_bounds__(256) void conv_silu_kernel(
    const float* __restrict__ zx, const float* __restrict__ cw,
    const float* __restrict__ cb, float* __restrict__ xc) {
  int idx = blockIdx.x * 256 + threadIdx.x;
  if (idx >= 2048 * 544) return;
  const int c4 = (idx % 544) << 2;
  const int row = idx / 544;
  const int t = row & (L_ - 1);
  float4 acc = *(const float4*)(cb + c4);
  float4 w0 = *(const float4*)(cw + (c4 + 0) * 4);
  float4 w1v = *(const float4*)(cw + (c4 + 1) * 4);
  float4 w2v = *(const float4*)(cw + (c4 + 2) * 4);
  float4 w3v = *(const float4*)(cw + (c4 + 3) * 4);
  const float wts[4][4] = {{w0.x, w0.y, w0.z, w0.w},
                           {w1v.x, w1v.y, w1v.z, w1v.w},
                           {w2v.x, w2v.y, w2v.z, w2v.w},
                           {w3v.x, w3v.y, w3v.z, w3v.w}};
  #pragma unroll
  for (int i = 0; i < 4; ++i) {
    int tau = t - 3 + i;
    if (tau >= 0) {
      float4 xv = *(const float4*)(zx + (long)(row - t + tau) * ZXS + DI + c4);
      acc.x = fmaf(xv.x, wts[0][i], acc.x);
      acc.y = fmaf(xv.y, wts[1][i], acc.y);
      acc.z = fmaf(xv.z, wts[2][i], acc.z);
      acc.w = fmaf(xv.w, wts[3][i], acc.w);
    }
  }
  acc.x = acc.x / (1.f + expf(-acc.x));
  acc.y = acc.y / (1.f + expf(-acc.y));
  acc.z = acc.z / (1.f + expf(-acc.z));
  acc.w = acc.w / (1.f + expf(-acc.w));
  *(float4*)(xc + (long)row * CONVD + c4) = acc;
}

// ================= chunked SSD scan (dt/softplus fused into wave0) =================
__global__ __launch_bounds__(256) void ssd_chunk_kernel(
    const float* __restrict__ xc, const float* __restrict__ zx,
    const float* __restrict__ dt_bias, const float* __restrict__ A_log,
    float* __restrict__ yss, float* __restrict__ Sbuf,
    float* __restrict__ EGbuf, float* __restrict__ Lam) {
  const int c = blockIdx.x & 15;
  const int h = (blockIdx.x >> 4) & 31;
  const int b = blockIdx.x >> 9;
  const int bh = b * NH + h;
  const long crow = (long)b * L_ + c * 64;
  const int tid = threadIdx.x, lane = tid & 63, wave = tid >> 6;

  __shared__ u16 Cs[64][72], Bs[64][72], Xt[64][72], Btw[64][72], Ms[64][72];
  __shared__ float Gs[64], wjL[64], dtL[64];

  if (wave == 0) {
    float draw = zx[(crow + lane) * ZXS + (DI + CONVD) + h] + dt_bias[h];
    float dt = (draw > 20.f) ? draw : log1pf(expf(draw));
    float g = -expf(A_log[h]) * dt;
    float G = g;
    #pragma unroll
    for (int off = 1; off < 64; off <<= 1) {
      float t = __shfl_up(G, off, 64);
      if (lane >= off) G += t;
    }
    float G63 = __shfl(G, 63, 64);
    Gs[lane] = G;
    wjL[lane] = expf(G63 - G) * dt;
    dtL[lane] = dt;
    EGbuf[(bh * 16 + c) * 64 + lane] = expf(G);
    if (lane == 63) Lam[bh * 16 + c] = expf(G63);
  }
  __syncthreads();
  for (int idx = tid; idx < 1024; idx += 256) {
    int r = idx >> 4, c4 = (idx & 15) << 2;
    const float* row = xc + (crow + r) * CONVD;
    float4 xv = *(const float4*)(row + h * HD + c4);
    Xt[c4 + 0][r] = f2bf(xv.x); Xt[c4 + 1][r] = f2bf(xv.y);
    Xt[c4 + 2][r] = f2bf(xv.z); Xt[c4 + 3][r] = f2bf(xv.w);
    float4 bv = *(const float4*)(row + DI + c4);
    *(ushort4*)&Bs[r][c4] = make_ushort4(f2bf(bv.x), f2bf(bv.y), f2bf(bv.z), f2bf(bv.w));
    float w = wjL[r];
    Btw[c4 + 0][r] = f2bf(bv.x * w); Btw[c4 + 1][r] = f2bf(bv.y * w);
    Btw[c4 + 2][r] = f2bf(bv.z * w); Btw[c4 + 3][r] = f2bf(bv.w * w);
    float4 cv = *(const float4*)(row + DI + DSTATE + c4);
    *(ushort4*)&Cs[r][c4] = make_ushort4(f2bf(cv.x), f2bf(cv.y), f2bf(cv.z), f2bf(cv.w));
  }
  __syncthreads();

  const int mrow = wave * 16 + (lane & 15);
  const int quad = lane >> 4;
  f32x4 accE[4];
  #pragma unroll
  for (int j = 0; j < 4; ++j) accE[j] = (f32x4){0.f, 0.f, 0.f, 0.f};
  #pragma unroll
  for (int ks = 0; ks < 2; ++ks) {
    int k0 = ks * 32 + quad * 8;
    bf16x8 a = *(const bf16x8*)&Cs[mrow][k0];
    #pragma unroll
    for (int j = 0; j < 4; ++j) {
      bf16x8 bfr = *(const bf16x8*)&Bs[j * 16 + (lane & 15)][k0];
      accE[j] = __builtin_amdgcn_mfma_f32_16x16x32_bf16(a, bfr, accE[j], 0, 0, 0);
    }
  }
  #pragma unroll
  for (int j = 0; j < 4; ++j) {
    int jc = j * 16 + (lane & 15);
    float Gj = Gs[jc], dtj = dtL[jc];
    #pragma unroll
    for (int r = 0; r < 4; ++r) {
      int ir = wave * 16 + quad * 4 + r;
      float v = (ir >= jc) ? accE[j][r] * expf(Gs[ir] - Gj) * dtj : 0.f;
      Ms[ir][jc] = f2bf(v);
    }
  }
  __syncthreads();
  f32x4 accY[4], accS[4];
  #pragma unroll
  for (int j = 0; j < 4; ++j) { accY[j] = (f32x4){0.f,0.f,0.f,0.f}; accS[j] = (f32x4){0.f,0.f,0.f,0.f}; }
  #pragma unroll
  for (int ks = 0; ks < 2; ++ks) {
    int k0 = ks * 32 + quad * 8;
    bf16x8 aM = *(const bf16x8*)&Ms[mrow][k0];
    bf16x8 aX = *(const bf16x8*)&Xt[mrow][k0];
    #pragma unroll
    for (int j = 0; j < 4; ++j) {
      bf16x8 bX = *(const bf16x8*)&Xt[j * 16 + (lane & 15)][k0];
      bf16x8 bB = *(const bf16x8*)&Btw[j * 16 + (lane & 15)][k0];
      accY[j] = __builtin_amdgcn_mfma_f32_16x16x32_bf16(aM, bX, accY[j], 0, 0, 0);
      accS[j] = __builtin_amdgcn_mfma_f32_16x16x32_bf16(aX, bB, accS[j], 0, 0, 0);
    }
  }
  float* Sc = Sbuf + (long)(bh * 16 + c) * 4096;
  #pragma unroll
  for (int j = 0; j < 4; ++j) {
    int col = j * 16 + (lane & 15);
    #pragma unroll
    for (int r = 0; r < 4; ++r) {
      int mr = wave * 16 + quad * 4 + r;
      yss[(crow + mr) * DI + h * HD + col] = accY[j][r];
      Sc[mr * 64 + col] = accS[j][r];
    }
  }
}

// S2: parallel serial-combine: one thread per state element
__global__ __launch_bounds__(256) void ssd_combine_kernel(
    float* __restrict__ Sbuf, const float* __restrict__ Lam) {
  const int bh = blockIdx.x >> 4;
  const int e = (blockIdx.x & 15) * 256 + threadIdx.x;   // 0..4095
  float* base = Sbuf + (long)bh * 16 * 4096 + e;
  const float* lamp = Lam + bh * 16;
  float H = 0.f;
  for (int cc = 0; cc < 16; ++cc) {
    float lam = lamp[cc];
    float v = base[cc * 4096];
    base[cc * 4096] = H;
    H = fmaf(lam, H, v);
  }
}

__global__ __launch_bounds__(256) void ssd_final_kernel(
    const float* __restrict__ xc, const float* __restrict__ Sbuf,
    const float* __restrict__ EGbuf, const float* __restrict__ Dp,
    float* __restrict__ yss) {
  const int c = blockIdx.x & 15;
  const int h = (blockIdx.x >> 4) & 31;
  const int b = blockIdx.x >> 9;
  const int bh = b * NH + h;
  const long crow = (long)b * L_ + c * 64;
  const int tid = threadIdx.x, lane = tid & 63, wave = tid >> 6;
  __shared__ u16 Csc[64][72], Hs[64][72];
  __shared__ float egL[64];
  if (tid < 64) egL[tid] = EGbuf[(bh * 16 + c) * 64 + tid];
  __syncthreads();
  const float* Sc = Sbuf + (long)(bh * 16 + c) * 4096;
  for (int idx = tid; idx < 1024; idx += 256) {
    int r = idx >> 4, c4 = (idx & 15) << 2;
    float4 hv = *(const float4*)(Sc + r * 64 + c4);
    *(ushort4*)&Hs[r][c4] = make_ushort4(f2bf(hv.x), f2bf(hv.y), f2bf(hv.z), f2bf(hv.w));
    float eg = egL[r];
    float4 cv = *(const float4*)(xc + (crow + r) * CONVD + DI + DSTATE + c4);
    *(ushort4*)&Csc[r][c4] = make_ushort4(f2bf(cv.x * eg), f2bf(cv.y * eg),
                                          f2bf(cv.z * eg), f2bf(cv.w * eg));
  }
  __syncthreads();
  const int mrow = wave * 16 + (lane & 15);
  const int quad = lane >> 4;
  f32x4 acc[4];
  #pragma unroll
  for (int j = 0; j < 4; ++j) acc[j] = (f32x4){0.f, 0.f, 0.f, 0.f};
  #pragma unroll
  for (int ks = 0; ks < 2; ++ks) {
    int k0 = ks * 32 + quad * 8;
    bf16x8 a = *(const bf16x8*)&Csc[mrow][k0];
    #pragma unroll
    for (int j = 0; j < 4; ++j) {
      bf16x8 bfr = *(const bf16x8*)&Hs[j * 16 + (lane & 15)][k0];
      acc[j] = __builtin_amdgcn_mfma_f32_16x16x32_bf16(a, bfr, acc[j], 0, 0, 0);
    }
  }
  const float Dh = Dp[h];
  #pragma unroll
  for (int j = 0; j < 4; ++j) {
    int p = j * 16 + (lane & 15);
    #pragma unroll
    for (int r = 0; r < 4; ++r) {
      int ir = wave * 16 + quad * 4 + r;
      long o = (crow + ir) * DI + h * HD + p;
      float xval = xc[(crow + ir) * CONVD + h * HD + p];
      yss[o] = yss[o] + acc[j][r] + Dh * xval;
    }
  }
}

// ---------------- gated rmsnorm ----------------
__global__ __launch_bounds__(256) void gated_rms_kernel(
    const float* __restrict__ y, const float* __restrict__ zx,
    const float* __restrict__ wt, u16* __restrict__ out) {
  const int row = blockIdx.x;
  const int c = threadIdx.x << 3;
  const float* yr = y + (long)row * DI + c;
  const float* zr = zx + (long)row * ZXS + c;
  float v[8];
  float ss = 0.f;
  #pragma unroll
  for (int i = 0; i < 8; i += 4) {
    float4 y4 = *(const float4*)(yr + i);
    float4 z4 = *(const float4*)(zr + i);
    const float zz[4] = {z4.x, z4.y, z4.z, z4.w};
    const float yy[4] = {y4.x, y4.y, y4.z, y4.w};
    #pragma unroll
    for (int j = 0; j < 4; ++j) {
      float sg = zz[j] / (1.f + expf(-zz[j]));
      float val = yy[j] * sg;
      v[i + j] = val;
      ss += val * val;
    }
  }
  float tot = block_reduce_sum256(ss);
  float sc = rsqrtf(tot * (1.0f / DI) + 1e-5f);
  const float* wr = wt + c;
  *(ushort4*)(out + (long)row * DI + c) =
      make_ushort4(f2bf(v[0] * sc * wr[0]), f2bf(v[1] * sc * wr[1]),
                   f2bf(v[2] * sc * wr[2]), f2bf(v[3] * sc * wr[3]));
  *(ushort4*)(out + (long)row * DI + c + 4) =
      make_ushort4(f2bf(v[4] * sc * wr[4]), f2bf(v[5] * sc * wr[5]),
                   f2bf(v[6] * sc * wr[6]), f2bf(v[7] * sc * wr[7]));
}

extern "C" void kernel_launch(void* const* d_in, const int* in_sizes, int n_in,
                              void* d_out, int out_size, void* d_ws, size_t ws_size,
                              hipStream_t stream) {
  const float* x        = (const float*)d_in[0];
  const float* x_d      = (const float*)d_in[1];
  const float* norm_w   = (const float*)d_in[2];
  const float* W_in     = (const float*)d_in[3];
  const float* conv_w   = (const float*)d_in[4];
  const float* conv_b   = (const float*)d_in[5];
  const float* dt_bias  = (const float*)d_in[6];
  const float* A_log    = (const float*)d_in[7];
  const float* D_param  = (const float*)d_in[8];
  const float* ssm_w    = (const float*)d_in[9];
  const float* W_out    = (const float*)d_in[10];
  const float* w1       = (const float*)d_in[11];
  const float* w2       = (const float*)d_in[12];
  float* out = (float*)d_out;

  char* wsc = (char*)d_ws;
  size_t off = 0;
  auto alloc = [&](size_t n) { char* p = wsc + off; off += (n + 255) & ~(size_t)255; return p; };
  float* zx   = (float*)alloc((size_t)2048 * ZXS * 4);
  float* xc   = (float*)alloc((size_t)2048 * 2176 * 4);
  float* yss  = (float*)alloc((size_t)2048 * 2048 * 4);
  float* xf   = (float*)alloc((size_t)2048 * 1024 * 4);
  float* xa   = (float*)alloc((size_t)2048 * 1024 * 4);
  float* Sbuf = (float*)alloc((size_t)64 * 16 * 4096 * 4);
  float* EGbuf= (float*)alloc((size_t)65536 * 4);
  float* Lam  = (float*)alloc((size_t)1024 * 4);
  u16* xlnb   = (u16*)alloc((size_t)2048 * 1024 * 2);
  u16* ygnb   = (u16*)alloc((size_t)2048 * 2048 * 2);
  u16* xln2b  = (u16*)alloc((size_t)2048 * 1024 * 2);
  u16* Winb   = (u16*)alloc((size_t)4256 * 1024 * 2);
  u16* Woutb  = (u16*)alloc((size_t)1024 * 2048 * 2);
  u16* w12b   = (u16*)alloc((size_t)2048 * 1024 * 2);

  // 0) all weight conversions in one launch
  convert_weights<<<8352, 256, 0, stream>>>(W_in, W_out, w1, w2, Winb, Woutb, w12b);
  // 1) rmsnorm(x) -> bf16
  add_rms_kernel<<<2048, 256, 0, stream>>>(x, nullptr, nullptr, norm_w, xlnb, 1e-6f);
  // 2) in-proj: 128x64 tiles -> 1088 blocks
  gemm_lds<4, 2><<<dim3(68, 16), 256, 0, stream>>>(xlnb, Winb, zx, ZXS, 4256, 1024);
  // 3) conv+silu
  conv_silu_kernel<<<(2048 * 544 + 255) / 256, 256, 0, stream>>>(zx, conv_w, conv_b, xc);
  // 4) chunked SSD scan
  ssd_chunk_kernel<<<1024, 256, 0, stream>>>(xc, zx, dt_bias, A_log, yss, Sbuf, EGbuf, Lam);
  ssd_combine_kernel<<<1024, 256, 0, stream>>>(Sbuf, Lam);
  ssd_final_kernel<<<1024, 256, 0, stream>>>(xc, Sbuf, EGbuf, D_param, yss);
  // 5) gated rmsnorm -> bf16
  gated_rms_kernel<<<2048, 256, 0, stream>>>(yss, zx, ssm_w, ygnb);
  // 6) out-proj: 64x64 tiles -> 512 blocks
  gemm_lds<2, 2><<<dim3(16, 32), 256, 0, stream>>>(ygnb, Woutb, xf, 1024, 1024, 2048);
  // 7) x_a = x + x_f; rmsnorm -> bf16
  add_rms_kernel<<<2048, 256, 0, stream>>>(x, xf, xa, norm_w, xln2b, 1e-6f);
  // 8) fused MLP GEMM + gate + final outputs: 64x64 out-tiles -> 512 blocks
  gemm_mlp_final<<<dim3(16, 32), 256, 0, stream>>>(xln2b, w12b, xa, x_d, xf, out, 1024);
}

// Round 6
// 255.003 us; speedup vs baseline: 3.3703x; 1.0254x over previous
//
#include <hip/hip_runtime.h>

typedef unsigned short u16;
typedef __attribute__((ext_vector_type(8))) short bf16x8;
typedef __attribute__((ext_vector_type(4))) float f32x4;

#define B_      2
#define L_      1024
#define DM      1024
#define DI      2048
#define NH      32
#define HD      64
#define DSTATE  64
#define CONVD   2176
#define DPROJ   4256
#define ZXS     4352   // padded zx row stride (34*128)

__device__ __forceinline__ u16 f2bf(float f) {
  union { float f; unsigned u; } v; v.f = f;
  unsigned r = v.u + 0x7fffu + ((v.u >> 16) & 1u);   // RNE
  return (u16)(r >> 16);
}
__device__ __forceinline__ float bf2f(u16 b) {
  union { unsigned u; float f; } v; v.u = ((unsigned)b) << 16;
  return v.f;
}

__device__ __forceinline__ void load_lds16(const void* g, void* l) {
  __builtin_amdgcn_global_load_lds(
      (const __attribute__((address_space(1))) void*)g,
      (__attribute__((address_space(3))) void*)l, 16, 0, 0);
}

template<int P> __device__ __forceinline__ void wait_prefetch() {
  if constexpr (P == 4)      asm volatile("s_waitcnt vmcnt(4)\n\ts_barrier" ::: "memory");
  else if constexpr (P == 6) asm volatile("s_waitcnt vmcnt(6)\n\ts_barrier" ::: "memory");
  else if constexpr (P == 8) asm volatile("s_waitcnt vmcnt(8)\n\ts_barrier" ::: "memory");
}

__device__ __forceinline__ float block_reduce_sum256(float v) {
  #pragma unroll
  for (int off = 32; off > 0; off >>= 1) v += __shfl_down(v, off, 64);
  __shared__ float red[4];
  int lane = threadIdx.x & 63, w = threadIdx.x >> 6;
  if (lane == 0) red[w] = v;
  __syncthreads();
  return red[0] + red[1] + red[2] + red[3];
}

// ---------------- merged: rmsnorm(x) (blocks 0..2047) + weight convert (rest) ----------------
__global__ __launch_bounds__(256) void rms_and_convert(
    const float* __restrict__ x, const float* __restrict__ norm_w, u16* __restrict__ xlnb,
    const float* __restrict__ W_in, const float* __restrict__ W_out,
    const float* __restrict__ w1, const float* __restrict__ w2,
    u16* __restrict__ Winb, u16* __restrict__ Woutb, u16* __restrict__ w12b) {
  if (blockIdx.x < 2048) {
    const int row = blockIdx.x;
    const int c = threadIdx.x << 2;
    float4 v = *(const float4*)(x + (long)row * DM + c);
    float ss = v.x * v.x + v.y * v.y + v.z * v.z + v.w * v.w;
    float tot = block_reduce_sum256(ss);
    float sc = rsqrtf(tot * (1.0f / DM) + 1e-6f);
    float4 wv = *(const float4*)(norm_w + c);
    *(ushort4*)(xlnb + (long)row * DM + c) =
        make_ushort4(f2bf(v.x * sc * wv.x), f2bf(v.y * sc * wv.y),
                     f2bf(v.z * sc * wv.z), f2bf(v.w * sc * wv.w));
    return;
  }
  const long R0 = 4256L * 1024 / 4;
  const long R1 = R0 + 2048L * 1024 / 4;
  long i = (long)(blockIdx.x - 2048) * 256 + threadIdx.x;
  float4 v;
  ushort4* dst;
  if (i < R0) {
    v = ((const float4*)W_in)[i];
    dst = ((ushort4*)Winb) + i;
  } else if (i < R1) {
    long j = i - R0;
    v = ((const float4*)W_out)[j];
    dst = ((ushort4*)Woutb) + j;
  } else {
    long j = i - R1;
    long row = j >> 8;
    const float* s = (row < 1024) ? (w1 + row * 1024) : (w2 + (row - 1024) * 1024);
    v = ((const float4*)s)[j & 255];
    dst = ((ushort4*)w12b) + j;
  }
  *dst = make_ushort4(f2bf(v.x), f2bf(v.y), f2bf(v.z), f2bf(v.w));
}

// ---------------- rmsnorm with fused residual add (f32 in1 + f32 in2) ----------------
__global__ __launch_bounds__(256) void add_rms_kernel(
    const float* __restrict__ in1, const float* __restrict__ in2,
    float* __restrict__ sum_out, const float* __restrict__ wt,
    u16* __restrict__ out, float eps) {
  const int row = blockIdx.x;
  const int c = threadIdx.x << 2;
  float4 v = *(const float4*)(in1 + (long)row * DM + c);
  float4 u = *(const float4*)(in2 + (long)row * DM + c);
  v.x += u.x; v.y += u.y; v.z += u.z; v.w += u.w;
  *(float4*)(sum_out + (long)row * DM + c) = v;
  float ss = v.x * v.x + v.y * v.y + v.z * v.z + v.w * v.w;
  float tot = block_reduce_sum256(ss);
  float sc = rsqrtf(tot * (1.0f / DM) + eps);
  float4 wv = *(const float4*)(wt + c);
  *(ushort4*)(out + (long)row * DM + c) =
      make_ushort4(f2bf(v.x * sc * wv.x), f2bf(v.y * sc * wv.y),
                   f2bf(v.z * sc * wv.z), f2bf(v.w * sc * wv.w));
}

// ============ bf16 NT GEMM: tile (NI*32)x(NJ*32), dbuf LDS + vmcnt prefetch ============
// OUT: 0 = f32 store, 1 = bf16 store, 2 = f32 atomicAdd (split-K).
// Loop K = Ksub starting at blockIdx.z*Ksub; row stride = Kstride.
template<int NI, int NJ, int OUT>
__global__ __launch_bounds__(256) void gemm_lds(
    const u16* __restrict__ A, const u16* __restrict__ Bw,
    void* __restrict__ Cv, int N, int Nw, int Ksub, int Kstride) {
  constexpr int BM = NI * 32;
  constexpr int BN = NJ * 32;
  __shared__ u16 As[2][BM][64];
  __shared__ u16 Bs[2][BN][64];
  const int tid = threadIdx.x;
  const int lane = tid & 63;
  const int wave = tid >> 6;
  const int ml = lane & 15;
  const int quad = lane >> 4;
  const int wm = (wave & 1) * (NI * 16);
  const int wn = (wave >> 1) * (NJ * 16);
  const long bm = (long)blockIdx.y * BM;
  const long bn = (long)blockIdx.x * BN;
  const long koff = (long)blockIdx.z * Ksub;

  const int lr = lane >> 3;
  const int lc = (lane & 7) ^ lr;

  f32x4 acc[NI][NJ];
  #pragma unroll
  for (int i = 0; i < NI; ++i)
    #pragma unroll
    for (int j = 0; j < NJ; ++j)
      acc[i][j] = (f32x4){0.f, 0.f, 0.f, 0.f};

  auto stage = [&](int kk, int buf) {
    #pragma unroll
    for (int t = 0; t < BM / 32; ++t) {
      const int u = wave * (BM / 32) + t;
      load_lds16(A + (bm + u * 8 + lr) * Kstride + koff + kk + lc * 8, &As[buf][u * 8][0]);
    }
    #pragma unroll
    for (int t = 0; t < BN / 32; ++t) {
      const int u = wave * (BN / 32) + t;
      long brow = bn + u * 8 + lr;
      if (brow >= Nw) brow = Nw - 1;
      load_lds16(Bw + brow * Kstride + koff + kk + lc * 8, &Bs[buf][u * 8][0]);
    }
  };

  stage(0, 0);
  int buf = 0;
  for (int kt = 0; kt < Ksub; kt += 64) {
    if (kt + 64 < Ksub) {
      stage(kt + 64, buf ^ 1);
      wait_prefetch<NI + NJ>();
    } else {
      asm volatile("s_waitcnt vmcnt(0)\n\ts_barrier" ::: "memory");
    }
    #pragma unroll
    for (int ks = 0; ks < 2; ++ks) {
      const int c = ks * 4 + quad;
      const int pc = (c ^ (ml & 7)) << 3;
      bf16x8 af[NI], bfr[NJ];
      #pragma unroll
      for (int i = 0; i < NI; ++i)
        af[i] = *(const bf16x8*)&As[buf][wm + (i << 4) + ml][pc];
      #pragma unroll
      for (int j = 0; j < NJ; ++j)
        bfr[j] = *(const bf16x8*)&Bs[buf][wn + (j << 4) + ml][pc];
      #pragma unroll
      for (int i = 0; i < NI; ++i)
        #pragma unroll
        for (int j = 0; j < NJ; ++j)
          acc[i][j] = __builtin_amdgcn_mfma_f32_16x16x32_bf16(af[i], bfr[j], acc[i][j], 0, 0, 0);
    }
    asm volatile("s_barrier" ::: "memory");   // LDS WAR vs next iter's stage
    buf ^= 1;
  }

  const int rquad = quad << 2;
  #pragma unroll
  for (int i = 0; i < NI; ++i) {
    const long gm = bm + wm + (i << 4) + rquad;
    #pragma unroll
    for (int j = 0; j < NJ; ++j) {
      const long gn = bn + wn + (j << 4) + ml;
      #pragma unroll
      for (int r = 0; r < 4; ++r) {
        if constexpr (OUT == 0)
          ((float*)Cv)[(gm + r) * N + gn] = acc[i][j][r];
        else if constexpr (OUT == 1)
          ((u16*)Cv)[(gm + r) * N + gn] = f2bf(acc[i][j][r]);
        else
          atomicAdd(&((float*)Cv)[(gm + r) * N + gn], acc[i][j][r]);
      }
    }
  }
}

// ============ fused MLP GEMM + silu-gate + both outputs (g/h split tile) ============
__global__ __launch_bounds__(256) void gemm_mlp_final(
    const u16* __restrict__ A, const u16* __restrict__ Bw,
    const float* __restrict__ xa, const float* __restrict__ xd,
    const float* __restrict__ xf, float* __restrict__ out, int K) {
  __shared__ u16 As[2][64][64];
  __shared__ u16 Bs[2][128][64];
  const int tid = threadIdx.x;
  const int lane = tid & 63;
  const int wave = tid >> 6;
  const int ml = lane & 15;
  const int quad = lane >> 4;
  const int wm = (wave & 1) * 32;
  const int wn = (wave >> 1) * 32;
  const long bm = (long)blockIdx.y * 64;
  const long c0 = (long)blockIdx.x * 64;

  const int lr = lane >> 3;
  const int lc = (lane & 7) ^ lr;

  f32x4 acc[2][4];
  #pragma unroll
  for (int i = 0; i < 2; ++i)
    #pragma unroll
    for (int j = 0; j < 4; ++j)
      acc[i][j] = (f32x4){0.f, 0.f, 0.f, 0.f};

  auto stage = [&](int kk, int buf) {
    #pragma unroll
    for (int t = 0; t < 2; ++t) {
      const int u = wave * 2 + t;
      load_lds16(A + (bm + u * 8 + lr) * K + kk + lc * 8, &As[buf][u * 8][0]);
    }
    #pragma unroll
    for (int t = 0; t < 4; ++t) {
      const int u = wave * 4 + t;
      const int r = u * 8 + lr;
      const long grow = (r < 64) ? (c0 + r) : (1024 + c0 + (r - 64));
      load_lds16(Bw + grow * K + kk + lc * 8, &Bs[buf][u * 8][0]);
    }
  };

  stage(0, 0);
  int buf = 0;
  for (int kt = 0; kt < K; kt += 64) {
    if (kt + 64 < K) {
      stage(kt + 64, buf ^ 1);
      wait_prefetch<6>();
    } else {
      asm volatile("s_waitcnt vmcnt(0)\n\ts_barrier" ::: "memory");
    }
    #pragma unroll
    for (int ks = 0; ks < 2; ++ks) {
      const int c = ks * 4 + quad;
      const int pc = (c ^ (ml & 7)) << 3;
      bf16x8 af[2], bfr[4];
      #pragma unroll
      for (int i = 0; i < 2; ++i)
        af[i] = *(const bf16x8*)&As[buf][wm + (i << 4) + ml][pc];
      #pragma unroll
      for (int j = 0; j < 2; ++j) {
        bfr[j]     = *(const bf16x8*)&Bs[buf][wn + (j << 4) + ml][pc];
        bfr[j + 2] = *(const bf16x8*)&Bs[buf][64 + wn + (j << 4) + ml][pc];
      }
      #pragma unroll
      for (int i = 0; i < 2; ++i)
        #pragma unroll
        for (int j = 0; j < 4; ++j)
          acc[i][j] = __builtin_amdgcn_mfma_f32_16x16x32_bf16(af[i], bfr[j], acc[i][j], 0, 0, 0);
    }
    asm volatile("s_barrier" ::: "memory");
    buf ^= 1;
  }

  float* out1 = out + (long)B_ * L_ * DM;
  const int rquad = quad << 2;
  #pragma unroll
  for (int i = 0; i < 2; ++i) {
    const long gm = bm + wm + (i << 4) + rquad;
    #pragma unroll
    for (int jj = 0; jj < 2; ++jj) {
      const long col = c0 + wn + (jj << 4) + ml;
      #pragma unroll
      for (int r = 0; r < 4; ++r) {
        float g = acc[i][jj][r];
        float h = acc[i][jj + 2][r];
        float e = (g / (1.f + expf(-g))) * h;
        long o = (gm + r) * DM + col;
        out[o]  = xa[o] + e;
        out1[o] = xd[o] + xf[o] + e;
      }
    }
  }
}

// ---------------- depthwise causal conv (k=4) + silu, bf16 in/out ----------------
__global__ __launch_bounds__(256) void conv_silu_kernel(
    const u16* __restrict__ zx, const float* __restrict__ cw,
    const float* __restrict__ cb, u16* __restrict__ xc) {
  int idx = blockIdx.x * 256 + threadIdx.x;
  if (idx >= 2048 * 544) return;
  const int c4 = (idx % 544) << 2;
  const int row = idx / 544;
  const int t = row & (L_ - 1);
  float4 acc = *(const float4*)(cb + c4);
  float4 w0 = *(const float4*)(cw + (c4 + 0) * 4);
  float4 w1v = *(const float4*)(cw + (c4 + 1) * 4);
  float4 w2v = *(const float4*)(cw + (c4 + 2) * 4);
  float4 w3v = *(const float4*)(cw + (c4 + 3) * 4);
  const float wts[4][4] = {{w0.x, w0.y, w0.z, w0.w},
                           {w1v.x, w1v.y, w1v.z, w1v.w},
                           {w2v.x, w2v.y, w2v.z, w2v.w},
                           {w3v.x, w3v.y, w3v.z, w3v.w}};
  #pragma unroll
  for (int i = 0; i < 4; ++i) {
    int tau = t - 3 + i;
    if (tau >= 0) {
      ushort4 xb = *(const ushort4*)(zx + (long)(row - t + tau) * ZXS + DI + c4);
      acc.x = fmaf(bf2f(xb.x), wts[0][i], acc.x);
      acc.y = fmaf(bf2f(xb.y), wts[1][i], acc.y);
      acc.z = fmaf(bf2f(xb.z), wts[2][i], acc.z);
      acc.w = fmaf(bf2f(xb.w), wts[3][i], acc.w);
    }
  }
  acc.x = acc.x / (1.f + expf(-acc.x));
  acc.y = acc.y / (1.f + expf(-acc.y));
  acc.z = acc.z / (1.f + expf(-acc.z));
  acc.w = acc.w / (1.f + expf(-acc.w));
  *(ushort4*)(xc + (long)row * CONVD + c4) =
      make_ushort4(f2bf(acc.x), f2bf(acc.y), f2bf(acc.z), f2bf(acc.w));
}

// ================= chunked SSD scan =================
__global__ __launch_bounds__(256) void ssd_chunk_kernel(
    const u16* __restrict__ xc, const u16* __restrict__ zx,
    const float* __restrict__ dt_bias, const float* __restrict__ A_log,
    u16* __restrict__ yss, float* __restrict__ Sbuf,
    float* __restrict__ EGbuf, float* __restrict__ Lam) {
  const int c = blockIdx.x & 15;
  const int h = (blockIdx.x >> 4) & 31;
  const int b = blockIdx.x >> 9;
  const int bh = b * NH + h;
  const long crow = (long)b * L_ + c * 64;
  const int tid = threadIdx.x, lane = tid & 63, wave = tid >> 6;

  __shared__ u16 Cs[64][72], Bs[64][72], Xt[64][72], Btw[64][72], Ms[64][72];
  __shared__ float Gs[64], wjL[64], dtL[64];

  if (wave == 0) {
    float draw = bf2f(zx[(crow + lane) * ZXS + (DI + CONVD) + h]) + dt_bias[h];
    float dt = (draw > 20.f) ? draw : log1pf(expf(draw));
    float g = -expf(A_log[h]) * dt;
    float G = g;
    #pragma unroll
    for (int off = 1; off < 64; off <<= 1) {
      float t = __shfl_up(G, off, 64);
      if (lane >= off) G += t;
    }
    float G63 = __shfl(G, 63, 64);
    Gs[lane] = G;
    wjL[lane] = expf(G63 - G) * dt;
    dtL[lane] = dt;
    EGbuf[(bh * 16 + c) * 64 + lane] = expf(G);
    if (lane == 63) Lam[bh * 16 + c] = expf(G63);
  }
  __syncthreads();
  for (int idx = tid; idx < 1024; idx += 256) {
    int r = idx >> 4, c4 = (idx & 15) << 2;
    const u16* row = xc + (crow + r) * CONVD;
    ushort4 xv = *(const ushort4*)(row + h * HD + c4);
    Xt[c4 + 0][r] = xv.x; Xt[c4 + 1][r] = xv.y;
    Xt[c4 + 2][r] = xv.z; Xt[c4 + 3][r] = xv.w;
    ushort4 bv = *(const ushort4*)(row + DI + c4);
    *(ushort4*)&Bs[r][c4] = bv;
    float w = wjL[r];
    Btw[c4 + 0][r] = f2bf(bf2f(bv.x) * w); Btw[c4 + 1][r] = f2bf(bf2f(bv.y) * w);
    Btw[c4 + 2][r] = f2bf(bf2f(bv.z) * w); Btw[c4 + 3][r] = f2bf(bf2f(bv.w) * w);
    *(ushort4*)&Cs[r][c4] = *(const ushort4*)(row + DI + DSTATE + c4);
  }
  __syncthreads();

  const int mrow = wave * 16 + (lane & 15);
  const int quad = lane >> 4;
  f32x4 accE[4];
  #pragma unroll
  for (int j = 0; j < 4; ++j) accE[j] = (f32x4){0.f, 0.f, 0.f, 0.f};
  #pragma unroll
  for (int ks = 0; ks < 2; ++ks) {
    int k0 = ks * 32 + quad * 8;
    bf16x8 a = *(const bf16x8*)&Cs[mrow][k0];
    #pragma unroll
    for (int j = 0; j < 4; ++j) {
      bf16x8 bfr = *(const bf16x8*)&Bs[j * 16 + (lane & 15)][k0];
      accE[j] = __builtin_amdgcn_mfma_f32_16x16x32_bf16(a, bfr, accE[j], 0, 0, 0);
    }
  }
  #pragma unroll
  for (int j = 0; j < 4; ++j) {
    int jc = j * 16 + (lane & 15);
    float Gj = Gs[jc], dtj = dtL[jc];
    #pragma unroll
    for (int r = 0; r < 4; ++r) {
      int ir = wave * 16 + quad * 4 + r;
      float v = (ir >= jc) ? accE[j][r] * expf(Gs[ir] - Gj) * dtj : 0.f;
      Ms[ir][jc] = f2bf(v);
    }
  }
  __syncthreads();
  f32x4 accY[4], accS[4];
  #pragma unroll
  for (int j = 0; j < 4; ++j) { accY[j] = (f32x4){0.f,0.f,0.f,0.f}; accS[j] = (f32x4){0.f,0.f,0.f,0.f}; }
  #pragma unroll
  for (int ks = 0; ks < 2; ++ks) {
    int k0 = ks * 32 + quad * 8;
    bf16x8 aM = *(const bf16x8*)&Ms[mrow][k0];
    bf16x8 aX = *(const bf16x8*)&Xt[mrow][k0];
    #pragma unroll
    for (int j = 0; j < 4; ++j) {
      bf16x8 bX = *(const bf16x8*)&Xt[j * 16 + (lane & 15)][k0];
      bf16x8 bB = *(const bf16x8*)&Btw[j * 16 + (lane & 15)][k0];
      accY[j] = __builtin_amdgcn_mfma_f32_16x16x32_bf16(aM, bX, accY[j], 0, 0, 0);
      accS[j] = __builtin_amdgcn_mfma_f32_16x16x32_bf16(aX, bB, accS[j], 0, 0, 0);
    }
  }
  float* Sc = Sbuf + (long)(bh * 16 + c) * 4096;
  #pragma unroll
  for (int j = 0; j < 4; ++j) {
    int col = j * 16 + (lane & 15);
    #pragma unroll
    for (int r = 0; r < 4; ++r) {
      int mr = wave * 16 + quad * 4 + r;
      yss[(crow + mr) * DI + h * HD + col] = f2bf(accY[j][r]);
      Sc[mr * 64 + col] = accS[j][r];
    }
  }
}

// S2: parallel serial-combine
__global__ __launch_bounds__(256) void ssd_combine_kernel(
    float* __restrict__ Sbuf, const float* __restrict__ Lam) {
  const int bh = blockIdx.x >> 4;
  const int e = (blockIdx.x & 15) * 256 + threadIdx.x;
  float* base = Sbuf + (long)bh * 16 * 4096 + e;
  const float* lamp = Lam + bh * 16;
  float H = 0.f;
  for (int cc = 0; cc < 16; ++cc) {
    float lam = lamp[cc];
    float v = base[cc * 4096];
    base[cc * 4096] = H;
    H = fmaf(lam, H, v);
  }
}

__global__ __launch_bounds__(256) void ssd_final_kernel(
    const u16* __restrict__ xc, const float* __restrict__ Sbuf,
    const float* __restrict__ EGbuf, const float* __restrict__ Dp,
    u16* __restrict__ yss) {
  const int c = blockIdx.x & 15;
  const int h = (blockIdx.x >> 4) & 31;
  const int b = blockIdx.x >> 9;
  const int bh = b * NH + h;
  const long crow = (long)b * L_ + c * 64;
  const int tid = threadIdx.x, lane = tid & 63, wave = tid >> 6;
  __shared__ u16 Csc[64][72], Hs[64][72];
  __shared__ float egL[64];
  if (tid < 64) egL[tid] = EGbuf[(bh * 16 + c) * 64 + tid];
  __syncthreads();
  const float* Sc = Sbuf + (long)(bh * 16 + c) * 4096;
  for (int idx = tid; idx < 1024; idx += 256) {
    int r = idx >> 4, c4 = (idx & 15) << 2;
    float4 hv = *(const float4*)(Sc + r * 64 + c4);
    *(ushort4*)&Hs[r][c4] = make_ushort4(f2bf(hv.x), f2bf(hv.y), f2bf(hv.z), f2bf(hv.w));
    float eg = egL[r];
    ushort4 cv = *(const ushort4*)(xc + (crow + r) * CONVD + DI + DSTATE + c4);
    *(ushort4*)&Csc[r][c4] = make_ushort4(f2bf(bf2f(cv.x) * eg), f2bf(bf2f(cv.y) * eg),
                                          f2bf(bf2f(cv.z) * eg), f2bf(bf2f(cv.w) * eg));
  }
  __syncthreads();
  const int mrow = wave * 16 + (lane & 15);
  const int quad = lane >> 4;
  f32x4 acc[4];
  #pragma unroll
  for (int j = 0; j < 4; ++j) acc[j] = (f32x4){0.f, 0.f, 0.f, 0.f};
  #pragma unroll
  for (int ks = 0; ks < 2; ++ks) {
    int k0 = ks * 32 + quad * 8;
    bf16x8 a = *(const bf16x8*)&Csc[mrow][k0];
    #pragma unroll
    for (int j = 0; j < 4; ++j) {
      bf16x8 bfr = *(const bf16x8*)&Hs[j * 16 + (lane & 15)][k0];
      acc[j] = __builtin_amdgcn_mfma_f32_16x16x32_bf16(a, bfr, acc[j], 0, 0, 0);
    }
  }
  const float Dh = Dp[h];
  #pragma unroll
  for (int j = 0; j < 4; ++j) {
    int p = j * 16 + (lane & 15);
    #pragma unroll
    for (int r = 0; r < 4; ++r) {
      int ir = wave * 16 + quad * 4 + r;
      long o = (crow + ir) * DI + h * HD + p;
      float xval = bf2f(xc[(crow + ir) * CONVD + h * HD + p]);
      yss[o] = f2bf(bf2f(yss[o]) + acc[j][r] + Dh * xval);
    }
  }
}

// ---------------- gated rmsnorm (bf16 y,z) + zero xf for split-K atomics ----------------
__global__ __launch_bounds__(256) void gated_rms_kernel(
    const u16* __restrict__ y, const u16* __restrict__ zx,
    const float* __restrict__ wt, u16* __restrict__ out,
    float* __restrict__ xf_zero) {
  const int row = blockIdx.x;
  const int c = threadIdx.x << 3;
  const u16* yr = y + (long)row * DI + c;
  const u16* zr = zx + (long)row * ZXS + c;
  *(float4*)(xf_zero + (long)row * DM + (threadIdx.x << 2)) = make_float4(0.f, 0.f, 0.f, 0.f);
  float v[8];
  float ss = 0.f;
  #pragma unroll
  for (int i = 0; i < 8; i += 4) {
    ushort4 y4 = *(const ushort4*)(yr + i);
    ushort4 z4 = *(const ushort4*)(zr + i);
    const float zz[4] = {bf2f(z4.x), bf2f(z4.y), bf2f(z4.z), bf2f(z4.w)};
    const float yy[4] = {bf2f(y4.x), bf2f(y4.y), bf2f(y4.z), bf2f(y4.w)};
    #pragma unroll
    for (int j = 0; j < 4; ++j) {
      float sg = zz[j] / (1.f + expf(-zz[j]));
      float val = yy[j] * sg;
      v[i + j] = val;
      ss += val * val;
    }
  }
  float tot = block_reduce_sum256(ss);
  float sc = rsqrtf(tot * (1.0f / DI) + 1e-5f);
  const float* wr = wt + c;
  *(ushort4*)(out + (long)row * DI + c) =
      make_ushort4(f2bf(v[0] * sc * wr[0]), f2bf(v[1] * sc * wr[1]),
                   f2bf(v[2] * sc * wr[2]), f2bf(v[3] * sc * wr[3]));
  *(ushort4*)(out + (long)row * DI + c + 4) =
      make_ushort4(f2bf(v[4] * sc * wr[4]), f2bf(v[5] * sc * wr[5]),
                   f2bf(v[6] * sc * wr[6]), f2bf(v[7] * sc * wr[7]));
}

extern "C" void kernel_launch(void* const* d_in, const int* in_sizes, int n_in,
                              void* d_out, int out_size, void* d_ws, size_t ws_size,
                              hipStream_t stream) {
  const float* x        = (const float*)d_in[0];
  const float* x_d      = (const float*)d_in[1];
  const float* norm_w   = (const float*)d_in[2];
  const float* W_in     = (const float*)d_in[3];
  const float* conv_w   = (const float*)d_in[4];
  const float* conv_b   = (const float*)d_in[5];
  const float* dt_bias  = (const float*)d_in[6];
  const float* A_log    = (const float*)d_in[7];
  const float* D_param  = (const float*)d_in[8];
  const float* ssm_w    = (const float*)d_in[9];
  const float* W_out    = (const float*)d_in[10];
  const float* w1       = (const float*)d_in[11];
  const float* w2       = (const float*)d_in[12];
  float* out = (float*)d_out;

  char* wsc = (char*)d_ws;
  size_t off = 0;
  auto alloc = [&](size_t n) { char* p = wsc + off; off += (n + 255) & ~(size_t)255; return p; };
  u16*   zx   = (u16*)alloc((size_t)2048 * ZXS * 2);
  u16*   xc   = (u16*)alloc((size_t)2048 * 2176 * 2);
  u16*   yss  = (u16*)alloc((size_t)2048 * 2048 * 2);
  float* xf   = (float*)alloc((size_t)2048 * 1024 * 4);
  float* xa   = (float*)alloc((size_t)2048 * 1024 * 4);
  float* Sbuf = (float*)alloc((size_t)64 * 16 * 4096 * 4);
  float* EGbuf= (float*)alloc((size_t)65536 * 4);
  float* Lam  = (float*)alloc((size_t)1024 * 4);
  u16* xlnb   = (u16*)alloc((size_t)2048 * 1024 * 2);
  u16* ygnb   = (u16*)alloc((size_t)2048 * 2048 * 2);
  u16* xln2b  = (u16*)alloc((size_t)2048 * 1024 * 2);
  u16* Winb   = (u16*)alloc((size_t)4256 * 1024 * 2);
  u16* Woutb  = (u16*)alloc((size_t)1024 * 2048 * 2);
  u16* w12b   = (u16*)alloc((size_t)2048 * 1024 * 2);

  // 0+1) rmsnorm(x) + all weight conversions, one launch
  rms_and_convert<<<2048 + 8352, 256, 0, stream>>>(x, norm_w, xlnb,
      W_in, W_out, w1, w2, Winb, Woutb, w12b);
  // 2) in-proj -> bf16 zx (padded stride)
  gemm_lds<4, 2, 1><<<dim3(68, 16), 256, 0, stream>>>(xlnb, Winb, zx, ZXS, 4256, 1024, 1024);
  // 3) conv+silu (bf16 in/out)
  conv_silu_kernel<<<(2048 * 544 + 255) / 256, 256, 0, stream>>>(zx, conv_w, conv_b, xc);
  // 4) chunked SSD scan (bf16 xc/yss)
  ssd_chunk_kernel<<<1024, 256, 0, stream>>>(xc, zx, dt_bias, A_log, yss, Sbuf, EGbuf, Lam);
  ssd_combine_kernel<<<1024, 256, 0, stream>>>(Sbuf, Lam);
  ssd_final_kernel<<<1024, 256, 0, stream>>>(xc, Sbuf, EGbuf, D_param, yss);
  // 5) gated rmsnorm -> bf16 (+ zeroes xf for split-K)
  gated_rms_kernel<<<2048, 256, 0, stream>>>(yss, zx, ssm_w, ygnb, xf);
  // 6) out-proj: split-K=2, 64x64 tiles -> 1024 blocks, atomicAdd into xf
  gemm_lds<2, 2, 2><<<dim3(16, 32, 2), 256, 0, stream>>>(ygnb, Woutb, xf, 1024, 1024, 1024, 2048);
  // 7) x_a = x + x_f; rmsnorm -> bf16
  add_rms_kernel<<<2048, 256, 0, stream>>>(x, xf, xa, norm_w, xln2b, 1e-6f);
  // 8) fused MLP GEMM + gate + final outputs
  gemm_mlp_final<<<dim3(16, 32), 256, 0, stream>>>(xln2b, w12b, xa, x_d, xf, out, 1024);
}